// Round 12
// baseline (3841.858 us; speedup 1.0000x reference)
//
#include <hip/hip_runtime.h>
#include <cmath>

#define BATCH 2048
#define FDIM  512
#define TDIM  100
#define H1    1024
#define H2    512
#define H3    256
#define ODIM  2
#define M_ALL (TDIM * BATCH)   // 204800 GEMM rows

typedef __attribute__((ext_vector_type(8))) _Float16 f16x8;
typedef __attribute__((ext_vector_type(4))) _Float16 f16x4;
typedef __attribute__((ext_vector_type(4))) float f32x4;
typedef __attribute__((ext_vector_type(4))) int i32x4;

struct W100 { float w[TDIM]; };

__device__ __forceinline__ void gl16(const void* g, void* l) {
  __builtin_amdgcn_global_load_lds(
      (const __attribute__((address_space(1))) unsigned int*)g,
      (__attribute__((address_space(3))) unsigned int*)l, 16, 0, 0);
}

// LIF update exactly mirroring the reference order
__device__ __forceinline__ void lif_update(float c, float& v, float& i, float& z) {
  float vd = v + 0.1f * (i - v);
  float id = 0.8f * i;
  z = (vd - 1.0f) > 0.0f ? 1.0f : 0.0f;
  v = (z != 0.0f) ? 0.0f : vd;
  i = id + c;
}

__global__ void zero_kernel(float* __restrict__ p, int n) {
  for (int i = blockIdx.x * blockDim.x + threadIdx.x; i < n; i += gridDim.x * blockDim.x)
    p[i] = 0.0f;
}

// Full-T transpose+split: x (B,F,T) -> xp K-TILED [2][FDIM/64][M_ALL][64] fp16 planes.
__global__ void tchunk_kernel(const float* __restrict__ x, _Float16* __restrict__ xp) {
  __shared__ float tile[64][105];
  const int kt = blockIdx.x;
  const int f0 = kt * 64;
  const int b  = blockIdx.y;
  const int tid = threadIdx.x;
  const size_t xb = (size_t)b * FDIM * TDIM;
  for (int idx = tid; idx < 1600; idx += 256) {       // 64 rows x 25 float4
    const int f = idx / 25, q = idx % 25;
    float4 v = *reinterpret_cast<const float4*>(&x[xb + (size_t)(f0 + f) * TDIM + q * 4]);
    tile[f][q * 4 + 0] = v.x; tile[f][q * 4 + 1] = v.y;
    tile[f][q * 4 + 2] = v.z; tile[f][q * 4 + 3] = v.w;
  }
  __syncthreads();
  const size_t PS = (size_t)M_ALL * FDIM;
  for (int idx = tid; idx < 1600; idx += 256) {       // 100 t x 16 f-quads
    const int t = idx >> 4, fq = idx & 15;
    f16x4 h, m;
    #pragma unroll
    for (int j = 0; j < 4; ++j) {
      float xa = tile[fq * 4 + j][t] * 64.0f;
      _Float16 hh = (_Float16)xa;
      float rm = (xa - (float)hh) * 4096.0f;
      h[j] = hh;
      m[j] = (_Float16)rm;
    }
    const size_t o = ((size_t)kt * M_ALL + (size_t)t * BATCH + b) * 64 + fq * 4;
    *reinterpret_cast<f16x4*>(&xp[o])      = h;
    *reinterpret_cast<f16x4*>(&xp[PS + o]) = m;
  }
}

// Layer-1 fold: BN scales folded, then per-row fp16 2-plane split with per-row pow2 scale.
__global__ void fold1_f16(const float* __restrict__ W1, const float* __restrict__ b1,
                          const float* __restrict__ g1, const float* __restrict__ bb1,
                          const float* __restrict__ m1, const float* __restrict__ v1,
                          const float* __restrict__ gi, const float* __restrict__ bi,
                          const float* __restrict__ mi, const float* __restrict__ vi,
                          _Float16* __restrict__ W1p, float* __restrict__ s1,
                          float* __restrict__ e1) {
  __shared__ float swf[FDIM];
  __shared__ float red[8];
  __shared__ float bsw[1];
  const int j = blockIdx.x, tid = threadIdx.x;
  const float sg = g1[j] / sqrtf(v1[j] + 1e-5f);
  float part = 0.0f, pmax = 0.0f;
  for (int f = tid; f < FDIM; f += 256) {
    float si = gi[f] / sqrtf(vi[f] + 1e-5f);
    float h0 = bi[f] - mi[f] * si;
    float w  = W1[j * FDIM + f];
    part += w * h0;
    float wf = w * si * sg;
    swf[f] = wf;
    pmax = fmaxf(pmax, fabsf(wf));
  }
  #pragma unroll
  for (int s = 1; s < 64; s <<= 1) {
    part += __shfl_xor(part, s);
    pmax = fmaxf(pmax, __shfl_xor(pmax, s));
  }
  if ((tid & 63) == 0) { red[tid >> 6] = part; red[4 + (tid >> 6)] = pmax; }
  __syncthreads();
  if (tid == 0) {
    float d = red[0] + red[1] + red[2] + red[3];
    e1[j] = (d + b1[j] - m1[j]) * sg + bb1[j];
    float mx = fmaxf(fmaxf(red[4], red[5]), fmaxf(red[6], red[7]));
    int e = 0;
    if (mx > 0.0f) frexpf(mx, &e);
    s1[j] = exp2f((float)(e - 11));       // combine scale: 2^(e-5) * 2^-6 (A-side 64)
    bsw[0] = exp2f((float)(5 - e));       // |wf * SW| <= 32
  }
  __syncthreads();
  const float SW = bsw[0];
  const size_t PS = (size_t)H1 * FDIM;
  for (int f = tid; f < FDIM; f += 256) {
    float wa = swf[f] * SW;
    _Float16 wh = (_Float16)wa;
    float r = (wa - (float)wh) * 4096.0f;
    W1p[(size_t)j * FDIM + f]      = wh;
    W1p[PS + (size_t)j * FDIM + f] = (_Float16)r;
  }
}

// Layers 2/3 fold: per-row 28-bit integer quantization into 4 signed-7-bit i8 digit planes.
__global__ void foldS_i8(const float* __restrict__ W, const float* __restrict__ b,
                         const float* __restrict__ g, const float* __restrict__ bb,
                         const float* __restrict__ m, const float* __restrict__ v,
                         signed char* __restrict__ Wq, float* __restrict__ qs,
                         float* __restrict__ e, int N, int K) {
  __shared__ float swf[1024];
  __shared__ float red[4];
  __shared__ int bse[1];
  const int j = blockIdx.x, tid = threadIdx.x;
  const float sg = g[j] / sqrtf(v[j] + 1e-5f);
  float pmax = 0.0f;
  for (int k = tid; k < K; k += 256) {
    float wf = W[(size_t)j * K + k] * sg;
    swf[k] = wf;
    pmax = fmaxf(pmax, fabsf(wf));
  }
  #pragma unroll
  for (int s = 1; s < 64; s <<= 1) pmax = fmaxf(pmax, __shfl_xor(pmax, s));
  if ((tid & 63) == 0) red[tid >> 6] = pmax;
  __syncthreads();
  if (tid == 0) {
    float mx = fmaxf(fmaxf(red[0], red[1]), fmaxf(red[2], red[3]));
    int ee = 0;
    if (mx > 0.0f) frexpf(mx, &ee);
    qs[j] = exp2f((float)(ee - 27));
    bse[0] = 27 - ee;
    e[j] = (b[j] - m[j]) * sg + bb[j];
  }
  __syncthreads();
  const double sc = ldexp(1.0, bse[0]);
  const size_t PS = (size_t)N * K;
  for (int k = tid; k < K; k += 256) {
    long D = llround((double)swf[k] * sc);   // |D| <= 2^27
    #pragma unroll
    for (int p = 0; p < 3; p++) {
      int d = (int)(D & 127);
      if (d >= 64) d -= 128;
      Wq[(size_t)p * PS + (size_t)j * K + k] = (signed char)d;
      D = (D - d) >> 7;
    }
    Wq[3 * PS + (size_t)j * K + k] = (signed char)D;  // |D| <= 64
  }
}

// Big GEMM1 (M_ALL x H1 x FDIM), fp16 2-plane x 2-plane (3 pairs) -> c1 fp32.
// 128x128 block, 4 waves, wave tile 64x64. BK=32 (32KB LDS -> ~4 blocks/CU).
// A K-TILED [2][8][M_ALL][64]; XCD swizzle. Accumulation order identical to BK=64.
__global__ __launch_bounds__(256, 3)
void g1c_kernel(const _Float16* __restrict__ A, const _Float16* __restrict__ Wp,
                const float* __restrict__ s1, const float* __restrict__ e1,
                float* __restrict__ cOut)
{
  constexpr int BM = 128, BN = 128, K = FDIM, N = H1, BK = 32;
  constexpr int FR = 4, FC = 4, WTM = 64, WTN = 64;
  __shared__ __align__(16) _Float16 As[2][BM][BK];
  __shared__ __align__(16) _Float16 Bs[2][BN][BK];
  const int tid = threadIdx.x, lane = tid & 63, wid = tid >> 6;
  const int wr = wid >> 1, wc = wid & 1;
  const int l16 = lane & 15, lq = lane >> 4;
  const int chunk = gridDim.x >> 3;
  const int flat = (blockIdx.x & 7) * chunk + (blockIdx.x >> 3);
  const int bnk = flat & 7, bmk = flat >> 3;
  const size_t APS = (size_t)M_ALL * FDIM;
  const size_t WPS = (size_t)N * K;
  const int lrow16 = lane >> 2;        // 0..15: row within 16-row group
  const int lslot4 = lane & 3;         // 16B slot 0..3

  f32x4 accA[FR][FC] = {}, accB[FR][FC] = {};

  // it = K-step of 32 (16 steps over K=512). A source: k-tile kt = it>>1, half = it&1.
  auto stage = [&](int it) {
    const int kt = it >> 1, kh32 = (it & 1) * 32;
    #pragma unroll
    for (int q = 0; q < 4; ++q) {              // A: 2 planes x 8 row-groups(16) / 4 waves
      int i = q * 4 + wid;
      int s = i >> 3, r0 = (i & 7) * 16;
      int row = r0 + lrow16;
      int ss = lslot4 ^ (row & 3);
      gl16(A + (size_t)s * APS + ((size_t)kt * M_ALL + (size_t)(bmk * BM + row)) * 64
               + kh32 + ss * 8,
           &As[s][r0][0]);
    }
    const int k0 = it * BK;
    #pragma unroll
    for (int q = 0; q < 4; ++q) {              // B: 2 planes x 8 row-groups(16) / 4 waves
      int i = q * 4 + wid;
      int s = i >> 3, r0 = (i & 7) * 16;
      int row = r0 + lrow16;
      int ss = lslot4 ^ (row & 3);
      gl16(Wp + (size_t)s * WPS + (size_t)(bnk * BN + row) * K + k0 + ss * 8, &Bs[s][r0][0]);
    }
  };

  auto loadA = [&](int s, int fr) -> f16x8 {
    int row = wr * WTM + fr * 16 + l16;
    int slot = lq ^ (row & 3);
    return *reinterpret_cast<const f16x8*>(&As[s][row][slot * 8]);
  };
  auto loadB = [&](int s, int fc) -> f16x8 {
    int row = wc * WTN + fc * 16 + l16;
    int slot = lq ^ (row & 3);
    return *reinterpret_cast<const f16x8*>(&Bs[s][row][slot * 8]);
  };

  stage(0);
  __syncthreads();
  constexpr int NK = K / BK;   // 16
  for (int it = 0; it < NK; ++it) {
    f16x8 af[2][FR], bf[2][FC];
    #pragma unroll
    for (int s = 0; s < 2; ++s) {
      #pragma unroll
      for (int fr = 0; fr < FR; ++fr) af[s][fr] = loadA(s, fr);
      #pragma unroll
      for (int fc = 0; fc < FC; ++fc) bf[s][fc] = loadB(s, fc);
    }
    __syncthreads();
    if (it + 1 < NK) stage(it + 1);
    #pragma unroll
    for (int fr = 0; fr < FR; ++fr)
      #pragma unroll
      for (int fc = 0; fc < FC; ++fc) {
        accA[fr][fc] = __builtin_amdgcn_mfma_f32_16x16x32_f16(af[0][fr], bf[0][fc], accA[fr][fc], 0, 0, 0);
        accB[fr][fc] = __builtin_amdgcn_mfma_f32_16x16x32_f16(af[0][fr], bf[1][fc], accB[fr][fc], 0, 0, 0);
        accB[fr][fc] = __builtin_amdgcn_mfma_f32_16x16x32_f16(af[1][fr], bf[0][fc], accB[fr][fc], 0, 0, 0);
      }
    __syncthreads();
  }

  #pragma unroll
  for (int fc = 0; fc < FC; ++fc) {
    const int n = bnk * BN + wc * WTN + fc * 16 + l16;
    const float eb = e1[n], sn = s1[n];
    #pragma unroll
    for (int fr = 0; fr < FR; ++fr) {
      const int row0 = bmk * BM + wr * WTM + fr * 16 + lq * 4;
      #pragma unroll
      for (int r = 0; r < 4; ++r)
        cOut[(size_t)(row0 + r) * N + n] =
            sn * (accA[fr][fc][r] + 0.000244140625f * accB[fr][fc][r]) + eb;
    }
  }
}

// Big GEMM2/3: i8 spikes (K-TILED [K/128][M_ALL][128]) x 4 i8 digit planes -> c fp32.
// BM=128 block, 4 waves, wave tile 64 x (BN/2).
template<int BM, int BN, int MINW>
__global__ __launch_bounds__(256, MINW)
void gSc_kernel(const signed char* __restrict__ A, const signed char* __restrict__ Wq,
                const float* __restrict__ qs, const float* __restrict__ eb_,
                float* __restrict__ cOut, const int N, const int K)
{
  constexpr int BKI = 128;
  constexpr int WTM = BM / 2, WTN = BN / 2, FR = WTM / 16, FC = WTN / 16;
  constexpr int RA = BM / 8, RB = BN / 8;
  __shared__ __align__(16) signed char As[BM][BKI];
  __shared__ __align__(16) signed char Bs[4][BN][BKI];
  const int tid = threadIdx.x, lane = tid & 63, wid = tid >> 6;
  const int wr = wid >> 1, wc = wid & 1;
  const int l16 = lane & 15, lq = lane >> 4;
  const int chunk = gridDim.x >> 3;
  const int flat = (blockIdx.x & 7) * chunk + (blockIdx.x >> 3);
  const int bnk = flat & 7, bmk = flat >> 3;
  const size_t WPS = (size_t)N * K;
  const int lrow8 = lane >> 3, lslot = lane & 7;

  i32x4 acc[4][FR][FC] = {};

  auto stage = [&](int it) {
    #pragma unroll
    for (int q = 0; q < RA / 4; ++q) {
      int i = q * 4 + wid;
      int r0 = i * 8, row = r0 + lrow8;
      int ss = lslot ^ (row & 7);
      gl16(A + ((size_t)it * M_ALL + (size_t)(bmk * BM + row)) * BKI + ss * 16, &As[r0][0]);
    }
    const int k0 = it * BKI;
    #pragma unroll
    for (int q = 0; q < RB; ++q) {
      int i = q * 4 + wid;
      int s = i / RB, r0 = (i % RB) * 8, row = r0 + lrow8;
      int ss = lslot ^ (row & 7);
      gl16(Wq + (size_t)s * WPS + (size_t)(bnk * BN + row) * K + k0 + ss * 16, &Bs[s][r0][0]);
    }
  };

  auto loadA = [&](int kh, int fr) -> i32x4 {
    int row = wr * WTM + fr * 16 + l16;
    int slot = ((kh << 2) | lq) ^ (row & 7);
    return *reinterpret_cast<const i32x4*>(&As[row][slot * 16]);
  };
  auto loadB = [&](int kh, int s, int fc) -> i32x4 {
    int row = wc * WTN + fc * 16 + l16;
    int slot = ((kh << 2) | lq) ^ (row & 7);
    return *reinterpret_cast<const i32x4*>(&Bs[s][row][slot * 16]);
  };

  stage(0);
  __syncthreads();
  const int NK = K / BKI;
  for (int it = 0; it < NK; ++it) {
    {
      i32x4 av[FR], bv[4][FC];
      #pragma unroll
      for (int fr = 0; fr < FR; ++fr) av[fr] = loadA(0, fr);
      #pragma unroll
      for (int s = 0; s < 4; ++s)
        #pragma unroll
        for (int fc = 0; fc < FC; ++fc) bv[s][fc] = loadB(0, s, fc);
      #pragma unroll
      for (int s = 0; s < 4; ++s)
        #pragma unroll
        for (int fr = 0; fr < FR; ++fr)
          #pragma unroll
          for (int fc = 0; fc < FC; ++fc)
            acc[s][fr][fc] = __builtin_amdgcn_mfma_i32_16x16x64_i8(av[fr], bv[s][fc], acc[s][fr][fc], 0, 0, 0);
    }
    {
      i32x4 av[FR], bv[4][FC];
      #pragma unroll
      for (int fr = 0; fr < FR; ++fr) av[fr] = loadA(1, fr);
      #pragma unroll
      for (int s = 0; s < 4; ++s)
        #pragma unroll
        for (int fc = 0; fc < FC; ++fc) bv[s][fc] = loadB(1, s, fc);
      __syncthreads();
      if (it + 1 < NK) stage(it + 1);
      #pragma unroll
      for (int s = 0; s < 4; ++s)
        #pragma unroll
        for (int fr = 0; fr < FR; ++fr)
          #pragma unroll
          for (int fc = 0; fc < FC; ++fc)
            acc[s][fr][fc] = __builtin_amdgcn_mfma_i32_16x16x64_i8(av[fr], bv[s][fc], acc[s][fr][fc], 0, 0, 0);
      __syncthreads();
    }
  }

  #pragma unroll
  for (int fc = 0; fc < FC; ++fc) {
    const int n = bnk * BN + wc * WTN + fc * 16 + l16;
    const float qv = qs[n], eb = eb_[n];
    #pragma unroll
    for (int fr = 0; fr < FR; ++fr) {
      const int row0 = bmk * BM + wr * WTM + fr * 16 + lq * 4;
      #pragma unroll
      for (int r = 0; r < 4; ++r) {
        int slo = acc[0][fr][fc][r] + (acc[1][fr][fc][r] << 7) + (acc[2][fr][fc][r] << 14);
        cOut[(size_t)(row0 + r) * N + n] =
            qv * fmaf(2097152.0f, (float)acc[3][fr][fc][r], (float)slo) + eb;
      }
    }
  }
}

// LIF scan over full T: c [T][B][H] fp32 -> z K-TILED [H/128][M_ALL][128] i8 (0/1).
__global__ void scan_lif_kernel(const float* __restrict__ c, signed char* __restrict__ z,
                                int H)
{
  const int NN = BATCH * H;
  const int i4 = (blockIdx.x * 256 + threadIdx.x) * 4;
  const int b = i4 / H, n = i4 % H;
  const size_t zb = (size_t)(n >> 7) * M_ALL;
  const int nw = n & 127;
  float4 v  = make_float4(0.f, 0.f, 0.f, 0.f);
  float4 ii = make_float4(0.f, 0.f, 0.f, 0.f);
  for (int t = 0; t < TDIM; ++t) {
    const size_t o = (size_t)t * NN + i4;
    float4 cc = *reinterpret_cast<const float4*>(&c[o]);
    float4 zz;
    lif_update(cc.x, v.x, ii.x, zz.x);
    lif_update(cc.y, v.y, ii.y, zz.y);
    lif_update(cc.z, v.z, ii.z, zz.z);
    lif_update(cc.w, v.w, ii.w, zz.w);
    unsigned pz = (zz.x != 0.f ? 1u : 0u) | (zz.y != 0.f ? 256u : 0u)
                | (zz.z != 0.f ? 65536u : 0u) | (zz.w != 0.f ? 16777216u : 0u);
    *reinterpret_cast<unsigned*>(&z[(zb + (size_t)t * BATCH + b) * 128 + nw]) = pz;
  }
}

// Fused scan3 + output layer over full T: per wave = one batch row b; lane owns 4 of H3.
__global__ void scan3out_kernel(const float* __restrict__ c3,
                                const float* __restrict__ Wout, const float* __restrict__ bout,
                                float* __restrict__ out, W100 wts)
{
  const int lane = threadIdx.x & 63, wv = threadIdx.x >> 6;
  const int b = blockIdx.x * 4 + wv;
  const int n0 = lane * 4;
  float4 v  = make_float4(0.f, 0.f, 0.f, 0.f);
  float4 ii = make_float4(0.f, 0.f, 0.f, 0.f);
  const float4 w0 = *reinterpret_cast<const float4*>(&Wout[n0]);
  const float4 w1 = *reinterpret_cast<const float4*>(&Wout[H3 + n0]);
  const float bo0 = bout[0], bo1 = bout[1];
  float vo0 = 0.f, io0 = 0.f, vo1 = 0.f, io1 = 0.f;
  float acc0 = 0.0f, acc1 = 0.0f;
  for (int t = 0; t < TDIM; ++t) {
    const size_t o = ((size_t)t * BATCH + b) * H3 + n0;
    float4 cc = *reinterpret_cast<const float4*>(&c3[o]);
    float4 zz;
    lif_update(cc.x, v.x, ii.x, zz.x);
    lif_update(cc.y, v.y, ii.y, zz.y);
    lif_update(cc.z, v.z, ii.z, zz.z);
    lif_update(cc.w, v.w, ii.w, zz.w);
    float s0 = fmaf(zz.x, w0.x, fmaf(zz.y, w0.y, fmaf(zz.z, w0.z, zz.w * w0.w)));
    float s1 = fmaf(zz.x, w1.x, fmaf(zz.y, w1.y, fmaf(zz.z, w1.z, zz.w * w1.w)));
    #pragma unroll
    for (int m = 1; m < 64; m <<= 1) {
      s0 += __shfl_xor(s0, m);
      s1 += __shfl_xor(s1, m);
    }
    float zo0, zo1;
    lif_update(s0 + bo0, vo0, io0, zo0);
    lif_update(s1 + bo1, vo1, io1, zo1);
    acc0 += zo0 * wts.w[t];
    acc1 += zo1 * wts.w[t];
  }
  if (lane == 0) {
    const int oidx = b * ODIM;
    out[oidx]     = acc0;
    out[oidx + 1] = acc1;
  }
}

// ---------------- fp32 fallback path (round-1 kernels) ----------------
__global__ void fold1_kernel(const float* __restrict__ W1, const float* __restrict__ b1,
                             const float* __restrict__ g1, const float* __restrict__ bb1,
                             const float* __restrict__ m1, const float* __restrict__ v1,
                             const float* __restrict__ gi, const float* __restrict__ bi,
                             const float* __restrict__ mi, const float* __restrict__ vi,
                             float* __restrict__ W1f, float* __restrict__ e1) {
  const int j = blockIdx.x;
  const int tid = threadIdx.x;
  const float sg = g1[j] / sqrtf(v1[j] + 1e-5f);
  float part = 0.0f;
  for (int f = tid; f < FDIM; f += 256) {
    float si = gi[f] / sqrtf(vi[f] + 1e-5f);
    float h0 = bi[f] - mi[f] * si;
    float w  = W1[j * FDIM + f];
    part += w * h0;
    W1f[j * FDIM + f] = w * si * sg;
  }
  #pragma unroll
  for (int m = 1; m < 64; m <<= 1) part += __shfl_xor(part, m);
  __shared__ float red[4];
  if ((tid & 63) == 0) red[tid >> 6] = part;
  __syncthreads();
  if (tid == 0) {
    float d = red[0] + red[1] + red[2] + red[3];
    e1[j] = (d + b1[j] - m1[j]) * sg + bb1[j];
  }
}

__global__ void foldS_kernel(const float* __restrict__ W, const float* __restrict__ b,
                             const float* __restrict__ g, const float* __restrict__ bb,
                             const float* __restrict__ m, const float* __restrict__ v,
                             float* __restrict__ Wf, float* __restrict__ e, int K) {
  const int j = blockIdx.x;
  const float sg = g[j] / sqrtf(v[j] + 1e-5f);
  for (int k = threadIdx.x; k < K; k += 256)
    Wf[j * K + k] = W[j * K + k] * sg;
  if (threadIdx.x == 0) e[j] = (b[j] - m[j]) * sg + bb[j];
}

template<int TM, int TN, bool CONTIG>
__global__ __launch_bounds__(256, 2)
void gemm_lif_kernel(const float* __restrict__ A, size_t ars, size_t acs,
                     const float* __restrict__ W, const float* __restrict__ ebias,
                     float* __restrict__ vst, float* __restrict__ ist,
                     float* __restrict__ zout, int N, int K)
{
  constexpr int BK = 16;
  constexpr int BM = 16 * TM;
  constexpr int BN = 16 * TN;
  __shared__ float As[BK][BM];
  __shared__ float Bs[BK][BN];
  const int tid = threadIdx.x;
  const int tx = tid & 15, ty = tid >> 4;
  const int bn = blockIdx.x, bm = blockIdx.y;
  const float* Ablk = A + (size_t)bm * BM * ars;
  const float* Wblk = W + (size_t)bn * BN * (size_t)K;

  float acc[TM][TN];
  #pragma unroll
  for (int r = 0; r < TM; r++)
    #pragma unroll
    for (int c = 0; c < TN; c++) acc[r][c] = 0.0f;

  for (int k0 = 0; k0 < K; k0 += BK) {
    if (CONTIG) {
      constexpr int A4 = BM * BK / 4;
      #pragma unroll
      for (int q = 0; q < A4 / 256; q++) {
        int idx = q * 256 + tid;
        int r = idx >> 2;
        int kq = (idx & 3) << 2;
        float4 val = *reinterpret_cast<const float4*>(Ablk + (size_t)r * ars + (size_t)(k0 + kq));
        As[kq + 0][r] = val.x; As[kq + 1][r] = val.y;
        As[kq + 2][r] = val.z; As[kq + 3][r] = val.w;
      }
    } else {
      #pragma unroll
      for (int q = 0; q < BM * BK / 256; q++) {
        int idx = q * 256 + tid;
        int r = idx >> 4;
        int kk = idx & 15;
        As[kk][r] = Ablk[(size_t)r * ars + (size_t)(k0 + kk) * acs];
      }
    }
    {
      int n  = tid >> 2;
      int kq = (tid & 3) << 2;
      float4 val = *reinterpret_cast<const float4*>(Wblk + (size_t)n * K + (size_t)(k0 + kq));
      Bs[kq + 0][n] = val.x; Bs[kq + 1][n] = val.y;
      Bs[kq + 2][n] = val.z; Bs[kq + 3][n] = val.w;
    }
    __syncthreads();
    #pragma unroll
    for (int kk = 0; kk < BK; kk++) {
      float a[TM], bv[TN];
      const float4* ap = reinterpret_cast<const float4*>(&As[kk][ty * TM]);
      *reinterpret_cast<float4*>(&a[0]) = ap[0];
      if (TM == 8) *reinterpret_cast<float4*>(&a[4]) = ap[1];
      *reinterpret_cast<float4*>(&bv[0]) = *reinterpret_cast<const float4*>(&Bs[kk][tx * TN]);
      #pragma unroll
      for (int r = 0; r < TM; r++)
        #pragma unroll
        for (int c = 0; c < TN; c++)
          acc[r][c] = fmaf(a[r], bv[c], acc[r][c]);
    }
    __syncthreads();
  }

  const int n0 = bn * BN + tx * TN;
  const float4 ev = *reinterpret_cast<const float4*>(ebias + n0);
  #pragma unroll
  for (int r = 0; r < TM; r++) {
    const int brow = bm * BM + ty * TM + r;
    const size_t idx = (size_t)brow * N + n0;
    float c0 = acc[r][0] + ev.x;
    float c1 = acc[r][1] + ev.y;
    float c2 = acc[r][2] + ev.z;
    float c3 = acc[r][3] + ev.w;
    float4 vv = *reinterpret_cast<const float4*>(vst + idx);
    float4 ii = *reinterpret_cast<const float4*>(ist + idx);
    float4 zz;
    lif_update(c0, vv.x, ii.x, zz.x);
    lif_update(c1, vv.y, ii.y, zz.y);
    lif_update(c2, vv.z, ii.z, zz.z);
    lif_update(c3, vv.w, ii.w, zz.w);
    *reinterpret_cast<float4*>(zout + idx) = zz;
    *reinterpret_cast<float4*>(vst  + idx) = vv;
    *reinterpret_cast<float4*>(ist  + idx) = ii;
  }
}

__global__ void out_kernel(const float* __restrict__ z3, const float* __restrict__ Wout,
                           const float* __restrict__ bout, float* __restrict__ vo,
                           float* __restrict__ io, float* __restrict__ acc, float wt) {
  const int idx = blockIdx.x * 256 + threadIdx.x;
  if (idx >= BATCH * ODIM) return;
  const int b = idx >> 1, o = idx & 1;
  const float4* zr = reinterpret_cast<const float4*>(z3 + (size_t)b * H3);
  const float4* wr = reinterpret_cast<const float4*>(Wout + o * H3);
  float s = 0.0f;
  #pragma unroll 4
  for (int k = 0; k < H3 / 4; k++) {
    float4 zv = zr[k], wv = wr[k];
    s += zv.x * wv.x + zv.y * wv.y + zv.z * wv.z + zv.w * wv.w;
  }
  float cin = s + bout[o];
  float v = vo[idx], i = io[idx], z;
  lif_update(cin, v, i, z);
  vo[idx] = v; io[idx] = i;
  acc[idx] += z * wt;
}

extern "C" void kernel_launch(void* const* d_in, const int* in_sizes, int n_in,
                              void* d_out, int out_size, void* d_ws, size_t ws_size,
                              hipStream_t stream) {
  const float* x     = (const float*)d_in[0];
  const float* bni_g = (const float*)d_in[1];
  const float* bni_b = (const float*)d_in[2];
  const float* bni_m = (const float*)d_in[3];
  const float* bni_v = (const float*)d_in[4];
  const float* W1    = (const float*)d_in[5];
  const float* b1    = (const float*)d_in[6];
  const float* bn1_g = (const float*)d_in[7];
  const float* bn1_b = (const float*)d_in[8];
  const float* bn1_m = (const float*)d_in[9];
  const float* bn1_v = (const float*)d_in[10];
  const float* W2    = (const float*)d_in[11];
  const float* b2    = (const float*)d_in[12];
  const float* bn2_g = (const float*)d_in[13];
  const float* bn2_b = (const float*)d_in[14];
  const float* bn2_m = (const float*)d_in[15];
  const float* bn2_v = (const float*)d_in[16];
  const float* W3    = (const float*)d_in[17];
  const float* b3    = (const float*)d_in[18];
  const float* bn3_g = (const float*)d_in[19];
  const float* bn3_b = (const float*)d_in[20];
  const float* bn3_m = (const float*)d_in[21];
  const float* bn3_v = (const float*)d_in[22];
  const float* Wout  = (const float*)d_in[23];
  const float* bout  = (const float*)d_in[24];
  float* out = (float*)d_out;

  float* ws = (float*)d_ws;
  size_t off = 0;
  auto alloc = [&](size_t n) { float* p = ws + off; off += n; return p; };

  // ---- single-chunk big-GEMM path with region aliasing ----
  float* e1 = alloc(H1);
  float* e2 = alloc(H2);
  float* e3 = alloc(H3);
  float* s1 = alloc(H1);
  float* q2 = alloc(H2);
  float* q3 = alloc(H3);
  unsigned char* base = (unsigned char*)(ws + off);
  size_t boff = 0;
  auto carve = [&](size_t bytes) {
    void* p = base + boff;
    boff += (bytes + 255) & ~(size_t)255;
    return p;
  };
  _Float16* W1p   = (_Float16*)carve((size_t)2 * H1 * FDIM * 2);
  signed char* W2q = (signed char*)carve((size_t)4 * H2 * H1);
  signed char* W3q = (signed char*)carve((size_t)4 * H3 * H2);
  signed char* z1  = (signed char*)carve((size_t)M_ALL * H1);
  signed char* z2  = (signed char*)carve((size_t)M_ALL * H2);
  void* regionA = carve((size_t)2 * M_ALL * FDIM * 2);   // Xp (fp16 2-plane) / c2 (fp32)
  void* regionB = carve((size_t)M_ALL * H1 * 4);         // c1 (fp32) / c3 (fp32)
  _Float16* Xp = (_Float16*)regionA;
  float* c2    = (float*)regionA;
  float* c1    = (float*)regionB;
  float* c3    = (float*)regionB;
  const size_t needed = off * sizeof(float) + boff;

  if (ws_size >= needed) {
    // folds (independent)
    fold1_f16<<<H1, 256, 0, stream>>>(W1, b1, bn1_g, bn1_b, bn1_m, bn1_v,
                                      bni_g, bni_b, bni_m, bni_v, W1p, s1, e1);
    foldS_i8<<<H2, 256, 0, stream>>>(W2, b2, bn2_g, bn2_b, bn2_m, bn2_v, W2q, q2, e2, H2, H1);
    foldS_i8<<<H3, 256, 0, stream>>>(W3, b3, bn3_g, bn3_b, bn3_m, bn3_v, W3q, q3, e3, H3, H2);

    // serial layer chain over the full T at once
    tchunk_kernel<<<dim3(FDIM / 64, BATCH), 256, 0, stream>>>(x, Xp);
    g1c_kernel<<<(H1 / 128) * (M_ALL / 128), 256, 0, stream>>>(Xp, W1p, s1, e1, c1);
    scan_lif_kernel<<<BATCH * H1 / 1024, 256, 0, stream>>>(c1, z1, H1);
    gSc_kernel<128, 64, 3><<<(H2 / 64) * (M_ALL / 128), 256, 0, stream>>>(z1, W2q, q2, e2, c2, H2, H1);
    scan_lif_kernel<<<BATCH * H2 / 1024, 256, 0, stream>>>(c2, z2, H2);
    gSc_kernel<128, 32, 3><<<(H3 / 32) * (M_ALL / 128), 256, 0, stream>>>(z2, W3q, q3, e3, c3, H3, H2);
    W100 wts;
    for (int t = 0; t < TDIM; ++t)
      wts.w[t] = (float)std::pow(0.995, (double)(TDIM - 1 - t));
    scan3out_kernel<<<BATCH / 4, 256, 0, stream>>>(c3, Wout, bout, out, wts);
    return;
  }

  // ---- fp32 fallback (strided GEMM1, no transpose) ----
  off = 0;
  float* W1f = alloc((size_t)H1 * FDIM);
  float* W2f = alloc((size_t)H2 * H1);
  float* W3f = alloc((size_t)H3 * H2);
  float* fe1 = alloc(H1);
  float* fe2 = alloc(H2);
  float* fe3 = alloc(H3);
  float* fv1 = alloc((size_t)BATCH * H1);
  float* fi1 = alloc((size_t)BATCH * H1);
  float* fv2 = alloc((size_t)BATCH * H2);
  float* fi2 = alloc((size_t)BATCH * H2);
  float* fv3 = alloc((size_t)BATCH * H3);
  float* fi3 = alloc((size_t)BATCH * H3);
  float* fvo = alloc((size_t)BATCH * ODIM);
  float* fio = alloc((size_t)BATCH * ODIM);
  float* fz1 = alloc((size_t)BATCH * H1);
  float* fz2 = alloc((size_t)BATCH * H2);
  float* fz3 = alloc((size_t)BATCH * H3);

  const int nstate = BATCH * (2 * H1 + 2 * H2 + 2 * H3 + 2 * ODIM);
  zero_kernel<<<2048, 256, 0, stream>>>(fv1, nstate);
  zero_kernel<<<16, 256, 0, stream>>>(out, BATCH * ODIM);

  fold1_kernel<<<H1, 256, 0, stream>>>(W1, b1, bn1_g, bn1_b, bn1_m, bn1_v,
                                       bni_g, bni_b, bni_m, bni_v, W1f, fe1);
  foldS_kernel<<<H2, 256, 0, stream>>>(W2, b2, bn2_g, bn2_b, bn2_m, bn2_v, W2f, fe2, H1);
  foldS_kernel<<<H3, 256, 0, stream>>>(W3, b3, bn3_g, bn3_b, bn3_m, bn3_v, W3f, fe3, H2);

  const dim3 fg1(H1 / 64, BATCH / 128);
  const dim3 fg2(H2 / 64, BATCH / 64);
  const dim3 fg3(H3 / 64, BATCH / 64);

  for (int t = 0; t < TDIM; t++) {
    gemm_lif_kernel<8, 4, false><<<fg1, 256, 0, stream>>>(
        x + t, (size_t)FDIM * TDIM, TDIM, W1f, fe1, fv1, fi1, fz1, H1, FDIM);
    gemm_lif_kernel<4, 4, true><<<fg2, 256, 0, stream>>>(fz1, H1, 1, W2f, fe2, fv2, fi2, fz2, H2, H1);
    gemm_lif_kernel<4, 4, true><<<fg3, 256, 0, stream>>>(fz2, H2, 1, W3f, fe3, fv3, fi3, fz3, H3, H2);
    float wt = (float)std::pow(0.995, (double)(TDIM - 1 - t));
    out_kernel<<<BATCH * ODIM / 256, 256, 0, stream>>>(fz3, Wout, bout, fvo, fio, out, wt);
  }
}

// Round 13
// 1993.723 us; speedup vs baseline: 1.9270x; 1.9270x over previous
//
#include <hip/hip_runtime.h>
#include <cmath>

#define BATCH 2048
#define FDIM  512
#define TDIM  100
#define H1    1024
#define H2    512
#define H3    256
#define ODIM  2
#define M_ALL (TDIM * BATCH)   // 204800 GEMM rows

typedef __attribute__((ext_vector_type(8))) _Float16 f16x8;
typedef __attribute__((ext_vector_type(4))) _Float16 f16x4;
typedef __attribute__((ext_vector_type(4))) float f32x4;
typedef __attribute__((ext_vector_type(4))) int i32x4;

struct W100 { float w[TDIM]; };

__device__ __forceinline__ void gl16(const void* g, void* l) {
  __builtin_amdgcn_global_load_lds(
      (const __attribute__((address_space(1))) unsigned int*)g,
      (__attribute__((address_space(3))) unsigned int*)l, 16, 0, 0);
}

// LIF update exactly mirroring the reference order
__device__ __forceinline__ void lif_update(float c, float& v, float& i, float& z) {
  float vd = v + 0.1f * (i - v);
  float id = 0.8f * i;
  z = (vd - 1.0f) > 0.0f ? 1.0f : 0.0f;
  v = (z != 0.0f) ? 0.0f : vd;
  i = id + c;
}

__global__ void zero_kernel(float* __restrict__ p, int n) {
  for (int i = blockIdx.x * blockDim.x + threadIdx.x; i < n; i += gridDim.x * blockDim.x)
    p[i] = 0.0f;
}

// Full-T transpose+split: x (B,F,T) -> xp K-TILED [2][FDIM/64][M_ALL][64] fp16 planes.
__global__ void tchunk_kernel(const float* __restrict__ x, _Float16* __restrict__ xp) {
  __shared__ float tile[64][105];
  const int kt = blockIdx.x;
  const int f0 = kt * 64;
  const int b  = blockIdx.y;
  const int tid = threadIdx.x;
  const size_t xb = (size_t)b * FDIM * TDIM;
  for (int idx = tid; idx < 1600; idx += 256) {       // 64 rows x 25 float4
    const int f = idx / 25, q = idx % 25;
    float4 v = *reinterpret_cast<const float4*>(&x[xb + (size_t)(f0 + f) * TDIM + q * 4]);
    tile[f][q * 4 + 0] = v.x; tile[f][q * 4 + 1] = v.y;
    tile[f][q * 4 + 2] = v.z; tile[f][q * 4 + 3] = v.w;
  }
  __syncthreads();
  const size_t PS = (size_t)M_ALL * FDIM;
  for (int idx = tid; idx < 1600; idx += 256) {       // 100 t x 16 f-quads
    const int t = idx >> 4, fq = idx & 15;
    f16x4 h, m;
    #pragma unroll
    for (int j = 0; j < 4; ++j) {
      float xa = tile[fq * 4 + j][t] * 64.0f;
      _Float16 hh = (_Float16)xa;
      float rm = (xa - (float)hh) * 4096.0f;
      h[j] = hh;
      m[j] = (_Float16)rm;
    }
    const size_t o = ((size_t)kt * M_ALL + (size_t)t * BATCH + b) * 64 + fq * 4;
    *reinterpret_cast<f16x4*>(&xp[o])      = h;
    *reinterpret_cast<f16x4*>(&xp[PS + o]) = m;
  }
}

// Layer-1 fold: BN scales folded, then per-row fp16 2-plane split with per-row pow2 scale.
__global__ void fold1_f16(const float* __restrict__ W1, const float* __restrict__ b1,
                          const float* __restrict__ g1, const float* __restrict__ bb1,
                          const float* __restrict__ m1, const float* __restrict__ v1,
                          const float* __restrict__ gi, const float* __restrict__ bi,
                          const float* __restrict__ mi, const float* __restrict__ vi,
                          _Float16* __restrict__ W1p, float* __restrict__ s1,
                          float* __restrict__ e1) {
  __shared__ float swf[FDIM];
  __shared__ float red[8];
  __shared__ float bsw[1];
  const int j = blockIdx.x, tid = threadIdx.x;
  const float sg = g1[j] / sqrtf(v1[j] + 1e-5f);
  float part = 0.0f, pmax = 0.0f;
  for (int f = tid; f < FDIM; f += 256) {
    float si = gi[f] / sqrtf(vi[f] + 1e-5f);
    float h0 = bi[f] - mi[f] * si;
    float w  = W1[j * FDIM + f];
    part += w * h0;
    float wf = w * si * sg;
    swf[f] = wf;
    pmax = fmaxf(pmax, fabsf(wf));
  }
  #pragma unroll
  for (int s = 1; s < 64; s <<= 1) {
    part += __shfl_xor(part, s);
    pmax = fmaxf(pmax, __shfl_xor(pmax, s));
  }
  if ((tid & 63) == 0) { red[tid >> 6] = part; red[4 + (tid >> 6)] = pmax; }
  __syncthreads();
  if (tid == 0) {
    float d = red[0] + red[1] + red[2] + red[3];
    e1[j] = (d + b1[j] - m1[j]) * sg + bb1[j];
    float mx = fmaxf(fmaxf(red[4], red[5]), fmaxf(red[6], red[7]));
    int e = 0;
    if (mx > 0.0f) frexpf(mx, &e);
    s1[j] = exp2f((float)(e - 11));       // combine scale: 2^(e-5) * 2^-6 (A-side 64)
    bsw[0] = exp2f((float)(5 - e));       // |wf * SW| <= 32
  }
  __syncthreads();
  const float SW = bsw[0];
  const size_t PS = (size_t)H1 * FDIM;
  for (int f = tid; f < FDIM; f += 256) {
    float wa = swf[f] * SW;
    _Float16 wh = (_Float16)wa;
    float r = (wa - (float)wh) * 4096.0f;
    W1p[(size_t)j * FDIM + f]      = wh;
    W1p[PS + (size_t)j * FDIM + f] = (_Float16)r;
  }
}

// Layers 2/3 fold: per-row 28-bit integer quantization into 4 signed-7-bit i8 digit planes.
__global__ void foldS_i8(const float* __restrict__ W, const float* __restrict__ b,
                         const float* __restrict__ g, const float* __restrict__ bb,
                         const float* __restrict__ m, const float* __restrict__ v,
                         signed char* __restrict__ Wq, float* __restrict__ qs,
                         float* __restrict__ e, int N, int K) {
  __shared__ float swf[1024];
  __shared__ float red[4];
  __shared__ int bse[1];
  const int j = blockIdx.x, tid = threadIdx.x;
  const float sg = g[j] / sqrtf(v[j] + 1e-5f);
  float pmax = 0.0f;
  for (int k = tid; k < K; k += 256) {
    float wf = W[(size_t)j * K + k] * sg;
    swf[k] = wf;
    pmax = fmaxf(pmax, fabsf(wf));
  }
  #pragma unroll
  for (int s = 1; s < 64; s <<= 1) pmax = fmaxf(pmax, __shfl_xor(pmax, s));
  if ((tid & 63) == 0) red[tid >> 6] = pmax;
  __syncthreads();
  if (tid == 0) {
    float mx = fmaxf(fmaxf(red[0], red[1]), fmaxf(red[2], red[3]));
    int ee = 0;
    if (mx > 0.0f) frexpf(mx, &ee);
    qs[j] = exp2f((float)(ee - 27));
    bse[0] = 27 - ee;
    e[j] = (b[j] - m[j]) * sg + bb[j];
  }
  __syncthreads();
  const double sc = ldexp(1.0, bse[0]);
  const size_t PS = (size_t)N * K;
  for (int k = tid; k < K; k += 256) {
    long D = llround((double)swf[k] * sc);   // |D| <= 2^27
    #pragma unroll
    for (int p = 0; p < 3; p++) {
      int d = (int)(D & 127);
      if (d >= 64) d -= 128;
      Wq[(size_t)p * PS + (size_t)j * K + k] = (signed char)d;
      D = (D - d) >> 7;
    }
    Wq[3 * PS + (size_t)j * K + k] = (signed char)D;  // |D| <= 64
  }
}

// Big GEMM1 (M_ALL x H1 x FDIM), fp16 2-plane x 2-plane (3 pairs) -> c1 fp32.
// 128x128 block, BK=64, 8 waves (512 thr), wave tile 64x32 (FR=4, FC=2).
// 2 blocks/CU -> 4 waves/SIMD. A K-TILED; XCD swizzle. Per-acc K-order identical to r11.
__global__ __launch_bounds__(512, 4)
void g1c_kernel(const _Float16* __restrict__ A, const _Float16* __restrict__ Wp,
                const float* __restrict__ s1, const float* __restrict__ e1,
                float* __restrict__ cOut)
{
  constexpr int BM = 128, BN = 128, K = FDIM, N = H1, BK = 64;
  constexpr int FR = 4, FC = 2, WTM = 64, WTN = 32;
  __shared__ __align__(16) _Float16 As[2][BM][BK];
  __shared__ __align__(16) _Float16 Bs[2][BN][BK];
  const int tid = threadIdx.x, lane = tid & 63, wid = tid >> 6;   // wid 0..7
  const int wr = wid >> 2, wc = wid & 3;                          // 2 m-halves x 4 n-quarters
  const int l16 = lane & 15, lq = lane >> 4;
  const int chunk = gridDim.x >> 3;
  const int flat = (blockIdx.x & 7) * chunk + (blockIdx.x >> 3);
  const int bnk = flat & 7, bmk = flat >> 3;
  const size_t APS = (size_t)M_ALL * FDIM;
  const size_t WPS = (size_t)N * K;
  const int lrow8 = lane >> 3, lslot = lane & 7;

  f32x4 accA[FR][FC] = {}, accB[FR][FC] = {};

  auto stage = [&](int it) {
    #pragma unroll
    for (int q = 0; q < 4; ++q) {              // A: 2 planes x 16 row-groups / 8 waves
      int i = q * 8 + wid;
      int s = i >> 4, r0 = (i & 15) * 8;
      int row = r0 + lrow8;
      int ss = lslot ^ (row & 7);
      gl16(A + (size_t)s * APS + ((size_t)it * M_ALL + (size_t)(bmk * BM + row)) * 64 + ss * 8,
           &As[s][r0][0]);
    }
    const int k0 = it * BK;
    #pragma unroll
    for (int q = 0; q < 4; ++q) {              // B: 2 planes x 16 row-groups / 8 waves
      int i = q * 8 + wid;
      int s = i >> 4, r0 = (i & 15) * 8;
      int row = r0 + lrow8;
      int ss = lslot ^ (row & 7);
      gl16(Wp + (size_t)s * WPS + (size_t)(bnk * BN + row) * K + k0 + ss * 8, &Bs[s][r0][0]);
    }
  };

  auto loadA = [&](int kh, int s, int fr) -> f16x8 {
    int row = wr * WTM + fr * 16 + l16;
    int slot = ((kh << 2) | lq) ^ (row & 7);
    return *reinterpret_cast<const f16x8*>(&As[s][row][slot * 8]);
  };
  auto loadB = [&](int kh, int s, int fc) -> f16x8 {
    int row = wc * WTN + fc * 16 + l16;
    int slot = ((kh << 2) | lq) ^ (row & 7);
    return *reinterpret_cast<const f16x8*>(&Bs[s][row][slot * 8]);
  };

  stage(0);
  __syncthreads();
  constexpr int NK = K / BK;
  for (int it = 0; it < NK; ++it) {
    {
      f16x8 af[2][FR], bf[2][FC];
      #pragma unroll
      for (int s = 0; s < 2; ++s) {
        #pragma unroll
        for (int fr = 0; fr < FR; ++fr) af[s][fr] = loadA(0, s, fr);
        #pragma unroll
        for (int fc = 0; fc < FC; ++fc) bf[s][fc] = loadB(0, s, fc);
      }
      #pragma unroll
      for (int fr = 0; fr < FR; ++fr)
        #pragma unroll
        for (int fc = 0; fc < FC; ++fc) {
          accA[fr][fc] = __builtin_amdgcn_mfma_f32_16x16x32_f16(af[0][fr], bf[0][fc], accA[fr][fc], 0, 0, 0);
          accB[fr][fc] = __builtin_amdgcn_mfma_f32_16x16x32_f16(af[0][fr], bf[1][fc], accB[fr][fc], 0, 0, 0);
          accB[fr][fc] = __builtin_amdgcn_mfma_f32_16x16x32_f16(af[1][fr], bf[0][fc], accB[fr][fc], 0, 0, 0);
        }
    }
    {
      f16x8 af[2][FR], bf[2][FC];
      #pragma unroll
      for (int s = 0; s < 2; ++s) {
        #pragma unroll
        for (int fr = 0; fr < FR; ++fr) af[s][fr] = loadA(1, s, fr);
        #pragma unroll
        for (int fc = 0; fc < FC; ++fc) bf[s][fc] = loadB(1, s, fc);
      }
      __syncthreads();
      if (it + 1 < NK) stage(it + 1);
      #pragma unroll
      for (int fr = 0; fr < FR; ++fr)
        #pragma unroll
        for (int fc = 0; fc < FC; ++fc) {
          accA[fr][fc] = __builtin_amdgcn_mfma_f32_16x16x32_f16(af[0][fr], bf[0][fc], accA[fr][fc], 0, 0, 0);
          accB[fr][fc] = __builtin_amdgcn_mfma_f32_16x16x32_f16(af[0][fr], bf[1][fc], accB[fr][fc], 0, 0, 0);
          accB[fr][fc] = __builtin_amdgcn_mfma_f32_16x16x32_f16(af[1][fr], bf[0][fc], accB[fr][fc], 0, 0, 0);
        }
      __syncthreads();
    }
  }

  #pragma unroll
  for (int fc = 0; fc < FC; ++fc) {
    const int n = bnk * BN + wc * WTN + fc * 16 + l16;
    const float eb = e1[n], sn = s1[n];
    #pragma unroll
    for (int fr = 0; fr < FR; ++fr) {
      const int row0 = bmk * BM + wr * WTM + fr * 16 + lq * 4;
      #pragma unroll
      for (int r = 0; r < 4; ++r)
        cOut[(size_t)(row0 + r) * N + n] =
            sn * (accA[fr][fc][r] + 0.000244140625f * accB[fr][fc][r]) + eb;
    }
  }
}

// Big GEMM2/3: i8 spikes (K-TILED [K/128][M_ALL][128]) x 4 i8 digit planes -> c fp32.
// BM=128 block, 4 waves, wave tile 64 x (BN/2).  (round-11 verified config)
template<int BM, int BN, int MINW>
__global__ __launch_bounds__(256, MINW)
void gSc_kernel(const signed char* __restrict__ A, const signed char* __restrict__ Wq,
                const float* __restrict__ qs, const float* __restrict__ eb_,
                float* __restrict__ cOut, const int N, const int K)
{
  constexpr int BKI = 128;
  constexpr int WTM = BM / 2, WTN = BN / 2, FR = WTM / 16, FC = WTN / 16;
  constexpr int RA = BM / 8, RB = BN / 8;
  __shared__ __align__(16) signed char As[BM][BKI];
  __shared__ __align__(16) signed char Bs[4][BN][BKI];
  const int tid = threadIdx.x, lane = tid & 63, wid = tid >> 6;
  const int wr = wid >> 1, wc = wid & 1;
  const int l16 = lane & 15, lq = lane >> 4;
  const int chunk = gridDim.x >> 3;
  const int flat = (blockIdx.x & 7) * chunk + (blockIdx.x >> 3);
  const int bnk = flat & 7, bmk = flat >> 3;
  const size_t WPS = (size_t)N * K;
  const int lrow8 = lane >> 3, lslot = lane & 7;

  i32x4 acc[4][FR][FC] = {};

  auto stage = [&](int it) {
    #pragma unroll
    for (int q = 0; q < RA / 4; ++q) {
      int i = q * 4 + wid;
      int r0 = i * 8, row = r0 + lrow8;
      int ss = lslot ^ (row & 7);
      gl16(A + ((size_t)it * M_ALL + (size_t)(bmk * BM + row)) * BKI + ss * 16, &As[r0][0]);
    }
    const int k0 = it * BKI;
    #pragma unroll
    for (int q = 0; q < RB; ++q) {
      int i = q * 4 + wid;
      int s = i / RB, r0 = (i % RB) * 8, row = r0 + lrow8;
      int ss = lslot ^ (row & 7);
      gl16(Wq + (size_t)s * WPS + (size_t)(bnk * BN + row) * K + k0 + ss * 16, &Bs[s][r0][0]);
    }
  };

  auto loadA = [&](int kh, int fr) -> i32x4 {
    int row = wr * WTM + fr * 16 + l16;
    int slot = ((kh << 2) | lq) ^ (row & 7);
    return *reinterpret_cast<const i32x4*>(&As[row][slot * 16]);
  };
  auto loadB = [&](int kh, int s, int fc) -> i32x4 {
    int row = wc * WTN + fc * 16 + l16;
    int slot = ((kh << 2) | lq) ^ (row & 7);
    return *reinterpret_cast<const i32x4*>(&Bs[s][row][slot * 16]);
  };

  stage(0);
  __syncthreads();
  const int NK = K / BKI;
  for (int it = 0; it < NK; ++it) {
    {
      i32x4 av[FR], bv[4][FC];
      #pragma unroll
      for (int fr = 0; fr < FR; ++fr) av[fr] = loadA(0, fr);
      #pragma unroll
      for (int s = 0; s < 4; ++s)
        #pragma unroll
        for (int fc = 0; fc < FC; ++fc) bv[s][fc] = loadB(0, s, fc);
      #pragma unroll
      for (int s = 0; s < 4; ++s)
        #pragma unroll
        for (int fr = 0; fr < FR; ++fr)
          #pragma unroll
          for (int fc = 0; fc < FC; ++fc)
            acc[s][fr][fc] = __builtin_amdgcn_mfma_i32_16x16x64_i8(av[fr], bv[s][fc], acc[s][fr][fc], 0, 0, 0);
    }
    {
      i32x4 av[FR], bv[4][FC];
      #pragma unroll
      for (int fr = 0; fr < FR; ++fr) av[fr] = loadA(1, fr);
      #pragma unroll
      for (int s = 0; s < 4; ++s)
        #pragma unroll
        for (int fc = 0; fc < FC; ++fc) bv[s][fc] = loadB(1, s, fc);
      __syncthreads();
      if (it + 1 < NK) stage(it + 1);
      #pragma unroll
      for (int s = 0; s < 4; ++s)
        #pragma unroll
        for (int fr = 0; fr < FR; ++fr)
          #pragma unroll
          for (int fc = 0; fc < FC; ++fc)
            acc[s][fr][fc] = __builtin_amdgcn_mfma_i32_16x16x64_i8(av[fr], bv[s][fc], acc[s][fr][fc], 0, 0, 0);
      __syncthreads();
    }
  }

  #pragma unroll
  for (int fc = 0; fc < FC; ++fc) {
    const int n = bnk * BN + wc * WTN + fc * 16 + l16;
    const float qv = qs[n], eb = eb_[n];
    #pragma unroll
    for (int fr = 0; fr < FR; ++fr) {
      const int row0 = bmk * BM + wr * WTM + fr * 16 + lq * 4;
      #pragma unroll
      for (int r = 0; r < 4; ++r) {
        int slo = acc[0][fr][fc][r] + (acc[1][fr][fc][r] << 7) + (acc[2][fr][fc][r] << 14);
        cOut[(size_t)(row0 + r) * N + n] =
            qv * fmaf(2097152.0f, (float)acc[3][fr][fc][r], (float)slo) + eb;
      }
    }
  }
}

// LIF scan over full T: c [T][B][H] fp32 -> z K-TILED [H/128][M_ALL][128] i8 (0/1).
__global__ void scan_lif_kernel(const float* __restrict__ c, signed char* __restrict__ z,
                                int H)
{
  const int NN = BATCH * H;
  const int i4 = (blockIdx.x * 256 + threadIdx.x) * 4;
  const int b = i4 / H, n = i4 % H;
  const size_t zb = (size_t)(n >> 7) * M_ALL;
  const int nw = n & 127;
  float4 v  = make_float4(0.f, 0.f, 0.f, 0.f);
  float4 ii = make_float4(0.f, 0.f, 0.f, 0.f);
  for (int t = 0; t < TDIM; ++t) {
    const size_t o = (size_t)t * NN + i4;
    float4 cc = *reinterpret_cast<const float4*>(&c[o]);
    float4 zz;
    lif_update(cc.x, v.x, ii.x, zz.x);
    lif_update(cc.y, v.y, ii.y, zz.y);
    lif_update(cc.z, v.z, ii.z, zz.z);
    lif_update(cc.w, v.w, ii.w, zz.w);
    unsigned pz = (zz.x != 0.f ? 1u : 0u) | (zz.y != 0.f ? 256u : 0u)
                | (zz.z != 0.f ? 65536u : 0u) | (zz.w != 0.f ? 16777216u : 0u);
    *reinterpret_cast<unsigned*>(&z[(zb + (size_t)t * BATCH + b) * 128 + nw]) = pz;
  }
}

// Fused scan3 + output layer over full T: per wave = one batch row b; lane owns 4 of H3.
__global__ void scan3out_kernel(const float* __restrict__ c3,
                                const float* __restrict__ Wout, const float* __restrict__ bout,
                                float* __restrict__ out, W100 wts)
{
  const int lane = threadIdx.x & 63, wv = threadIdx.x >> 6;
  const int b = blockIdx.x * 4 + wv;
  const int n0 = lane * 4;
  float4 v  = make_float4(0.f, 0.f, 0.f, 0.f);
  float4 ii = make_float4(0.f, 0.f, 0.f, 0.f);
  const float4 w0 = *reinterpret_cast<const float4*>(&Wout[n0]);
  const float4 w1 = *reinterpret_cast<const float4*>(&Wout[H3 + n0]);
  const float bo0 = bout[0], bo1 = bout[1];
  float vo0 = 0.f, io0 = 0.f, vo1 = 0.f, io1 = 0.f;
  float acc0 = 0.0f, acc1 = 0.0f;
  for (int t = 0; t < TDIM; ++t) {
    const size_t o = ((size_t)t * BATCH + b) * H3 + n0;
    float4 cc = *reinterpret_cast<const float4*>(&c3[o]);
    float4 zz;
    lif_update(cc.x, v.x, ii.x, zz.x);
    lif_update(cc.y, v.y, ii.y, zz.y);
    lif_update(cc.z, v.z, ii.z, zz.z);
    lif_update(cc.w, v.w, ii.w, zz.w);
    float s0 = fmaf(zz.x, w0.x, fmaf(zz.y, w0.y, fmaf(zz.z, w0.z, zz.w * w0.w)));
    float s1 = fmaf(zz.x, w1.x, fmaf(zz.y, w1.y, fmaf(zz.z, w1.z, zz.w * w1.w)));
    #pragma unroll
    for (int m = 1; m < 64; m <<= 1) {
      s0 += __shfl_xor(s0, m);
      s1 += __shfl_xor(s1, m);
    }
    float zo0, zo1;
    lif_update(s0 + bo0, vo0, io0, zo0);
    lif_update(s1 + bo1, vo1, io1, zo1);
    acc0 += zo0 * wts.w[t];
    acc1 += zo1 * wts.w[t];
  }
  if (lane == 0) {
    const int oidx = b * ODIM;
    out[oidx]     = acc0;
    out[oidx + 1] = acc1;
  }
}

// ---------------- fp32 fallback path (round-1 kernels) ----------------
__global__ void fold1_kernel(const float* __restrict__ W1, const float* __restrict__ b1,
                             const float* __restrict__ g1, const float* __restrict__ bb1,
                             const float* __restrict__ m1, const float* __restrict__ v1,
                             const float* __restrict__ gi, const float* __restrict__ bi,
                             const float* __restrict__ mi, const float* __restrict__ vi,
                             float* __restrict__ W1f, float* __restrict__ e1) {
  const int j = blockIdx.x;
  const int tid = threadIdx.x;
  const float sg = g1[j] / sqrtf(v1[j] + 1e-5f);
  float part = 0.0f;
  for (int f = tid; f < FDIM; f += 256) {
    float si = gi[f] / sqrtf(vi[f] + 1e-5f);
    float h0 = bi[f] - mi[f] * si;
    float w  = W1[j * FDIM + f];
    part += w * h0;
    W1f[j * FDIM + f] = w * si * sg;
  }
  #pragma unroll
  for (int m = 1; m < 64; m <<= 1) part += __shfl_xor(part, m);
  __shared__ float red[4];
  if ((tid & 63) == 0) red[tid >> 6] = part;
  __syncthreads();
  if (tid == 0) {
    float d = red[0] + red[1] + red[2] + red[3];
    e1[j] = (d + b1[j] - m1[j]) * sg + bb1[j];
  }
}

__global__ void foldS_kernel(const float* __restrict__ W, const float* __restrict__ b,
                             const float* __restrict__ g, const float* __restrict__ bb,
                             const float* __restrict__ m, const float* __restrict__ v,
                             float* __restrict__ Wf, float* __restrict__ e, int K) {
  const int j = blockIdx.x;
  const float sg = g[j] / sqrtf(v[j] + 1e-5f);
  for (int k = threadIdx.x; k < K; k += 256)
    Wf[j * K + k] = W[j * K + k] * sg;
  if (threadIdx.x == 0) e[j] = (b[j] - m[j]) * sg + bb[j];
}

template<int TM, int TN, bool CONTIG>
__global__ __launch_bounds__(256, 2)
void gemm_lif_kernel(const float* __restrict__ A, size_t ars, size_t acs,
                     const float* __restrict__ W, const float* __restrict__ ebias,
                     float* __restrict__ vst, float* __restrict__ ist,
                     float* __restrict__ zout, int N, int K)
{
  constexpr int BK = 16;
  constexpr int BM = 16 * TM;
  constexpr int BN = 16 * TN;
  __shared__ float As[BK][BM];
  __shared__ float Bs[BK][BN];
  const int tid = threadIdx.x;
  const int tx = tid & 15, ty = tid >> 4;
  const int bn = blockIdx.x, bm = blockIdx.y;
  const float* Ablk = A + (size_t)bm * BM * ars;
  const float* Wblk = W + (size_t)bn * BN * (size_t)K;

  float acc[TM][TN];
  #pragma unroll
  for (int r = 0; r < TM; r++)
    #pragma unroll
    for (int c = 0; c < TN; c++) acc[r][c] = 0.0f;

  for (int k0 = 0; k0 < K; k0 += BK) {
    if (CONTIG) {
      constexpr int A4 = BM * BK / 4;
      #pragma unroll
      for (int q = 0; q < A4 / 256; q++) {
        int idx = q * 256 + tid;
        int r = idx >> 2;
        int kq = (idx & 3) << 2;
        float4 val = *reinterpret_cast<const float4*>(Ablk + (size_t)r * ars + (size_t)(k0 + kq));
        As[kq + 0][r] = val.x; As[kq + 1][r] = val.y;
        As[kq + 2][r] = val.z; As[kq + 3][r] = val.w;
      }
    } else {
      #pragma unroll
      for (int q = 0; q < BM * BK / 256; q++) {
        int idx = q * 256 + tid;
        int r = idx >> 4;
        int kk = idx & 15;
        As[kk][r] = Ablk[(size_t)r * ars + (size_t)(k0 + kk) * acs];
      }
    }
    {
      int n  = tid >> 2;
      int kq = (tid & 3) << 2;
      float4 val = *reinterpret_cast<const float4*>(Wblk + (size_t)n * K + (size_t)(k0 + kq));
      Bs[kq + 0][n] = val.x; Bs[kq + 1][n] = val.y;
      Bs[kq + 2][n] = val.z; Bs[kq + 3][n] = val.w;
    }
    __syncthreads();
    #pragma unroll
    for (int kk = 0; kk < BK; kk++) {
      float a[TM], bv[TN];
      const float4* ap = reinterpret_cast<const float4*>(&As[kk][ty * TM]);
      *reinterpret_cast<float4*>(&a[0]) = ap[0];
      if (TM == 8) *reinterpret_cast<float4*>(&a[4]) = ap[1];
      *reinterpret_cast<float4*>(&bv[0]) = *reinterpret_cast<const float4*>(&Bs[kk][tx * TN]);
      #pragma unroll
      for (int r = 0; r < TM; r++)
        #pragma unroll
        for (int c = 0; c < TN; c++)
          acc[r][c] = fmaf(a[r], bv[c], acc[r][c]);
    }
    __syncthreads();
  }

  const int n0 = bn * BN + tx * TN;
  const float4 ev = *reinterpret_cast<const float4*>(ebias + n0);
  #pragma unroll
  for (int r = 0; r < TM; r++) {
    const int brow = bm * BM + ty * TM + r;
    const size_t idx = (size_t)brow * N + n0;
    float c0 = acc[r][0] + ev.x;
    float c1 = acc[r][1] + ev.y;
    float c2 = acc[r][2] + ev.z;
    float c3 = acc[r][3] + ev.w;
    float4 vv = *reinterpret_cast<const float4*>(vst + idx);
    float4 ii = *reinterpret_cast<const float4*>(ist + idx);
    float4 zz;
    lif_update(c0, vv.x, ii.x, zz.x);
    lif_update(c1, vv.y, ii.y, zz.y);
    lif_update(c2, vv.z, ii.z, zz.z);
    lif_update(c3, vv.w, ii.w, zz.w);
    *reinterpret_cast<float4*>(zout + idx) = zz;
    *reinterpret_cast<float4*>(vst  + idx) = vv;
    *reinterpret_cast<float4*>(ist  + idx) = ii;
  }
}

__global__ void out_kernel(const float* __restrict__ z3, const float* __restrict__ Wout,
                           const float* __restrict__ bout, float* __restrict__ vo,
                           float* __restrict__ io, float* __restrict__ acc, float wt) {
  const int idx = blockIdx.x * 256 + threadIdx.x;
  if (idx >= BATCH * ODIM) return;
  const int b = idx >> 1, o = idx & 1;
  const float4* zr = reinterpret_cast<const float4*>(z3 + (size_t)b * H3);
  const float4* wr = reinterpret_cast<const float4*>(Wout + o * H3);
  float s = 0.0f;
  #pragma unroll 4
  for (int k = 0; k < H3 / 4; k++) {
    float4 zv = zr[k], wv = wr[k];
    s += zv.x * wv.x + zv.y * wv.y + zv.z * wv.z + zv.w * wv.w;
  }
  float cin = s + bout[o];
  float v = vo[idx], i = io[idx], z;
  lif_update(cin, v, i, z);
  vo[idx] = v; io[idx] = i;
  acc[idx] += z * wt;
}

extern "C" void kernel_launch(void* const* d_in, const int* in_sizes, int n_in,
                              void* d_out, int out_size, void* d_ws, size_t ws_size,
                              hipStream_t stream) {
  const float* x     = (const float*)d_in[0];
  const float* bni_g = (const float*)d_in[1];
  const float* bni_b = (const float*)d_in[2];
  const float* bni_m = (const float*)d_in[3];
  const float* bni_v = (const float*)d_in[4];
  const float* W1    = (const float*)d_in[5];
  const float* b1    = (const float*)d_in[6];
  const float* bn1_g = (const float*)d_in[7];
  const float* bn1_b = (const float*)d_in[8];
  const float* bn1_m = (const float*)d_in[9];
  const float* bn1_v = (const float*)d_in[10];
  const float* W2    = (const float*)d_in[11];
  const float* b2    = (const float*)d_in[12];
  const float* bn2_g = (const float*)d_in[13];
  const float* bn2_b = (const float*)d_in[14];
  const float* bn2_m = (const float*)d_in[15];
  const float* bn2_v = (const float*)d_in[16];
  const float* W3    = (const float*)d_in[17];
  const float* b3    = (const float*)d_in[18];
  const float* bn3_g = (const float*)d_in[19];
  const float* bn3_b = (const float*)d_in[20];
  const float* bn3_m = (const float*)d_in[21];
  const float* bn3_v = (const float*)d_in[22];
  const float* Wout  = (const float*)d_in[23];
  const float* bout  = (const float*)d_in[24];
  float* out = (float*)d_out;

  float* ws = (float*)d_ws;
  size_t off = 0;
  auto alloc = [&](size_t n) { float* p = ws + off; off += n; return p; };

  // ---- single-chunk big-GEMM path with region aliasing ----
  float* e1 = alloc(H1);
  float* e2 = alloc(H2);
  float* e3 = alloc(H3);
  float* s1 = alloc(H1);
  float* q2 = alloc(H2);
  float* q3 = alloc(H3);
  unsigned char* base = (unsigned char*)(ws + off);
  size_t boff = 0;
  auto carve = [&](size_t bytes) {
    void* p = base + boff;
    boff += (bytes + 255) & ~(size_t)255;
    return p;
  };
  _Float16* W1p   = (_Float16*)carve((size_t)2 * H1 * FDIM * 2);
  signed char* W2q = (signed char*)carve((size_t)4 * H2 * H1);
  signed char* W3q = (signed char*)carve((size_t)4 * H3 * H2);
  signed char* z1  = (signed char*)carve((size_t)M_ALL * H1);
  signed char* z2  = (signed char*)carve((size_t)M_ALL * H2);
  void* regionA = carve((size_t)2 * M_ALL * FDIM * 2);   // Xp (fp16 2-plane) / c2 (fp32)
  void* regionB = carve((size_t)M_ALL * H1 * 4);         // c1 (fp32) / c3 (fp32)
  _Float16* Xp = (_Float16*)regionA;
  float* c2    = (float*)regionA;
  float* c1    = (float*)regionB;
  float* c3    = (float*)regionB;
  const size_t needed = off * sizeof(float) + boff;

  if (ws_size >= needed) {
    // folds (independent)
    fold1_f16<<<H1, 256, 0, stream>>>(W1, b1, bn1_g, bn1_b, bn1_m, bn1_v,
                                      bni_g, bni_b, bni_m, bni_v, W1p, s1, e1);
    foldS_i8<<<H2, 256, 0, stream>>>(W2, b2, bn2_g, bn2_b, bn2_m, bn2_v, W2q, q2, e2, H2, H1);
    foldS_i8<<<H3, 256, 0, stream>>>(W3, b3, bn3_g, bn3_b, bn3_m, bn3_v, W3q, q3, e3, H3, H2);

    // serial layer chain over the full T at once
    tchunk_kernel<<<dim3(FDIM / 64, BATCH), 256, 0, stream>>>(x, Xp);
    g1c_kernel<<<(H1 / 128) * (M_ALL / 128), 512, 0, stream>>>(Xp, W1p, s1, e1, c1);
    scan_lif_kernel<<<BATCH * H1 / 1024, 256, 0, stream>>>(c1, z1, H1);
    gSc_kernel<128, 64, 2><<<(H2 / 64) * (M_ALL / 128), 256, 0, stream>>>(z1, W2q, q2, e2, c2, H2, H1);
    scan_lif_kernel<<<BATCH * H2 / 1024, 256, 0, stream>>>(c2, z2, H2);
    gSc_kernel<128, 32, 3><<<(H3 / 32) * (M_ALL / 128), 256, 0, stream>>>(z2, W3q, q3, e3, c3, H3, H2);
    W100 wts;
    for (int t = 0; t < TDIM; ++t)
      wts.w[t] = (float)std::pow(0.995, (double)(TDIM - 1 - t));
    scan3out_kernel<<<BATCH / 4, 256, 0, stream>>>(c3, Wout, bout, out, wts);
    return;
  }

  // ---- fp32 fallback (strided GEMM1, no transpose) ----
  off = 0;
  float* W1f = alloc((size_t)H1 * FDIM);
  float* W2f = alloc((size_t)H2 * H1);
  float* W3f = alloc((size_t)H3 * H2);
  float* fe1 = alloc(H1);
  float* fe2 = alloc(H2);
  float* fe3 = alloc(H3);
  float* fv1 = alloc((size_t)BATCH * H1);
  float* fi1 = alloc((size_t)BATCH * H1);
  float* fv2 = alloc((size_t)BATCH * H2);
  float* fi2 = alloc((size_t)BATCH * H2);
  float* fv3 = alloc((size_t)BATCH * H3);
  float* fi3 = alloc((size_t)BATCH * H3);
  float* fvo = alloc((size_t)BATCH * ODIM);
  float* fio = alloc((size_t)BATCH * ODIM);
  float* fz1 = alloc((size_t)BATCH * H1);
  float* fz2 = alloc((size_t)BATCH * H2);
  float* fz3 = alloc((size_t)BATCH * H3);

  const int nstate = BATCH * (2 * H1 + 2 * H2 + 2 * H3 + 2 * ODIM);
  zero_kernel<<<2048, 256, 0, stream>>>(fv1, nstate);
  zero_kernel<<<16, 256, 0, stream>>>(out, BATCH * ODIM);

  fold1_kernel<<<H1, 256, 0, stream>>>(W1, b1, bn1_g, bn1_b, bn1_m, bn1_v,
                                       bni_g, bni_b, bni_m, bni_v, W1f, fe1);
  foldS_kernel<<<H2, 256, 0, stream>>>(W2, b2, bn2_g, bn2_b, bn2_m, bn2_v, W2f, fe2, H1);
  foldS_kernel<<<H3, 256, 0, stream>>>(W3, b3, bn3_g, bn3_b, bn3_m, bn3_v, W3f, fe3, H2);

  const dim3 fg1(H1 / 64, BATCH / 128);
  const dim3 fg2(H2 / 64, BATCH / 64);
  const dim3 fg3(H3 / 64, BATCH / 64);

  for (int t = 0; t < TDIM; t++) {
    gemm_lif_kernel<8, 4, false><<<fg1, 256, 0, stream>>>(
        x + t, (size_t)FDIM * TDIM, TDIM, W1f, fe1, fv1, fi1, fz1, H1, FDIM);
    gemm_lif_kernel<4, 4, true><<<fg2, 256, 0, stream>>>(fz1, H1, 1, W2f, fe2, fv2, fi2, fz2, H2, H1);
    gemm_lif_kernel<4, 4, true><<<fg3, 256, 0, stream>>>(fz2, H2, 1, W3f, fe3, fv3, fi3, fz3, H3, H2);
    float wt = (float)std::pow(0.995, (double)(TDIM - 1 - t));
    out_kernel<<<BATCH * ODIM / 256, 256, 0, stream>>>(fz3, Wout, bout, fvo, fio, out, wt);
  }
}

// Round 14
// 1771.874 us; speedup vs baseline: 2.1682x; 1.1252x over previous
//
#include <hip/hip_runtime.h>
#include <cmath>

#define BATCH 2048
#define FDIM  512
#define TDIM  100
#define H1    1024
#define H2    512
#define H3    256
#define ODIM  2
#define M_ALL (TDIM * BATCH)   // 204800 GEMM rows

typedef __attribute__((ext_vector_type(8))) _Float16 f16x8;
typedef __attribute__((ext_vector_type(4))) _Float16 f16x4;
typedef __attribute__((ext_vector_type(4))) float f32x4;
typedef __attribute__((ext_vector_type(16))) float f32x16;
typedef __attribute__((ext_vector_type(4))) int i32x4;

struct W100 { float w[TDIM]; };

__device__ __forceinline__ void gl16(const void* g, void* l) {
  __builtin_amdgcn_global_load_lds(
      (const __attribute__((address_space(1))) unsigned int*)g,
      (__attribute__((address_space(3))) unsigned int*)l, 16, 0, 0);
}

// LIF update exactly mirroring the reference order
__device__ __forceinline__ void lif_update(float c, float& v, float& i, float& z) {
  float vd = v + 0.1f * (i - v);
  float id = 0.8f * i;
  z = (vd - 1.0f) > 0.0f ? 1.0f : 0.0f;
  v = (z != 0.0f) ? 0.0f : vd;
  i = id + c;
}

__global__ void zero_kernel(float* __restrict__ p, int n) {
  for (int i = blockIdx.x * blockDim.x + threadIdx.x; i < n; i += gridDim.x * blockDim.x)
    p[i] = 0.0f;
}

// Full-T transpose+split: x (B,F,T) -> xp K-TILED [2][FDIM/64][M_ALL][64] fp16 planes.
__global__ void tchunk_kernel(const float* __restrict__ x, _Float16* __restrict__ xp) {
  __shared__ float tile[64][105];
  const int kt = blockIdx.x;
  const int f0 = kt * 64;
  const int b  = blockIdx.y;
  const int tid = threadIdx.x;
  const size_t xb = (size_t)b * FDIM * TDIM;
  for (int idx = tid; idx < 1600; idx += 256) {       // 64 rows x 25 float4
    const int f = idx / 25, q = idx % 25;
    float4 v = *reinterpret_cast<const float4*>(&x[xb + (size_t)(f0 + f) * TDIM + q * 4]);
    tile[f][q * 4 + 0] = v.x; tile[f][q * 4 + 1] = v.y;
    tile[f][q * 4 + 2] = v.z; tile[f][q * 4 + 3] = v.w;
  }
  __syncthreads();
  const size_t PS = (size_t)M_ALL * FDIM;
  for (int idx = tid; idx < 1600; idx += 256) {       // 100 t x 16 f-quads
    const int t = idx >> 4, fq = idx & 15;
    f16x4 h, m;
    #pragma unroll
    for (int j = 0; j < 4; ++j) {
      float xa = tile[fq * 4 + j][t] * 64.0f;
      _Float16 hh = (_Float16)xa;
      float rm = (xa - (float)hh) * 4096.0f;
      h[j] = hh;
      m[j] = (_Float16)rm;
    }
    const size_t o = ((size_t)kt * M_ALL + (size_t)t * BATCH + b) * 64 + fq * 4;
    *reinterpret_cast<f16x4*>(&xp[o])      = h;
    *reinterpret_cast<f16x4*>(&xp[PS + o]) = m;
  }
}

// Layer-1 fold: BN scales folded, then per-row fp16 2-plane split with per-row pow2 scale.
__global__ void fold1_f16(const float* __restrict__ W1, const float* __restrict__ b1,
                          const float* __restrict__ g1, const float* __restrict__ bb1,
                          const float* __restrict__ m1, const float* __restrict__ v1,
                          const float* __restrict__ gi, const float* __restrict__ bi,
                          const float* __restrict__ mi, const float* __restrict__ vi,
                          _Float16* __restrict__ W1p, float* __restrict__ s1,
                          float* __restrict__ e1) {
  __shared__ float swf[FDIM];
  __shared__ float red[8];
  __shared__ float bsw[1];
  const int j = blockIdx.x, tid = threadIdx.x;
  const float sg = g1[j] / sqrtf(v1[j] + 1e-5f);
  float part = 0.0f, pmax = 0.0f;
  for (int f = tid; f < FDIM; f += 256) {
    float si = gi[f] / sqrtf(vi[f] + 1e-5f);
    float h0 = bi[f] - mi[f] * si;
    float w  = W1[j * FDIM + f];
    part += w * h0;
    float wf = w * si * sg;
    swf[f] = wf;
    pmax = fmaxf(pmax, fabsf(wf));
  }
  #pragma unroll
  for (int s = 1; s < 64; s <<= 1) {
    part += __shfl_xor(part, s);
    pmax = fmaxf(pmax, __shfl_xor(pmax, s));
  }
  if ((tid & 63) == 0) { red[tid >> 6] = part; red[4 + (tid >> 6)] = pmax; }
  __syncthreads();
  if (tid == 0) {
    float d = red[0] + red[1] + red[2] + red[3];
    e1[j] = (d + b1[j] - m1[j]) * sg + bb1[j];
    float mx = fmaxf(fmaxf(red[4], red[5]), fmaxf(red[6], red[7]));
    int e = 0;
    if (mx > 0.0f) frexpf(mx, &e);
    s1[j] = exp2f((float)(e - 11));       // combine scale: 2^(e-5) * 2^-6 (A-side 64)
    bsw[0] = exp2f((float)(5 - e));       // |wf * SW| <= 32
  }
  __syncthreads();
  const float SW = bsw[0];
  const size_t PS = (size_t)H1 * FDIM;
  for (int f = tid; f < FDIM; f += 256) {
    float wa = swf[f] * SW;
    _Float16 wh = (_Float16)wa;
    float r = (wa - (float)wh) * 4096.0f;
    W1p[(size_t)j * FDIM + f]      = wh;
    W1p[PS + (size_t)j * FDIM + f] = (_Float16)r;
  }
}

// Layers 2/3 fold: per-row 28-bit integer quantization into 4 signed-7-bit i8 digit planes.
__global__ void foldS_i8(const float* __restrict__ W, const float* __restrict__ b,
                         const float* __restrict__ g, const float* __restrict__ bb,
                         const float* __restrict__ m, const float* __restrict__ v,
                         signed char* __restrict__ Wq, float* __restrict__ qs,
                         float* __restrict__ e, int N, int K) {
  __shared__ float swf[1024];
  __shared__ float red[4];
  __shared__ int bse[1];
  const int j = blockIdx.x, tid = threadIdx.x;
  const float sg = g[j] / sqrtf(v[j] + 1e-5f);
  float pmax = 0.0f;
  for (int k = tid; k < K; k += 256) {
    float wf = W[(size_t)j * K + k] * sg;
    swf[k] = wf;
    pmax = fmaxf(pmax, fabsf(wf));
  }
  #pragma unroll
  for (int s = 1; s < 64; s <<= 1) pmax = fmaxf(pmax, __shfl_xor(pmax, s));
  if ((tid & 63) == 0) red[tid >> 6] = pmax;
  __syncthreads();
  if (tid == 0) {
    float mx = fmaxf(fmaxf(red[0], red[1]), fmaxf(red[2], red[3]));
    int ee = 0;
    if (mx > 0.0f) frexpf(mx, &ee);
    qs[j] = exp2f((float)(ee - 27));
    bse[0] = 27 - ee;
    e[j] = (b[j] - m[j]) * sg + bb[j];
  }
  __syncthreads();
  const double sc = ldexp(1.0, bse[0]);
  const size_t PS = (size_t)N * K;
  for (int k = tid; k < K; k += 256) {
    long D = llround((double)swf[k] * sc);   // |D| <= 2^27
    #pragma unroll
    for (int p = 0; p < 3; p++) {
      int d = (int)(D & 127);
      if (d >= 64) d -= 128;
      Wq[(size_t)p * PS + (size_t)j * K + k] = (signed char)d;
      D = (D - d) >> 7;
    }
    Wq[3 * PS + (size_t)j * K + k] = (signed char)D;  // |D| <= 64
  }
}

// Big GEMM1 (M_ALL x H1 x FDIM), fp16 2-plane x 2-plane (3 pairs) -> c1 fp32.
// 128x128 block, 4 waves, wave tile 64x64 via 2x2 frags of 32x32 (mfma_32x32x16).
// A K-TILED; XCD swizzle; same LDS/staging/swizzle as r11.
__global__ __launch_bounds__(256, 2)
void g1c_kernel(const _Float16* __restrict__ A, const _Float16* __restrict__ Wp,
                const float* __restrict__ s1, const float* __restrict__ e1,
                float* __restrict__ cOut)
{
  constexpr int BM = 128, BN = 128, K = FDIM, N = H1, BK = 64;
  constexpr int FR = 2, FC = 2, WTM = 64, WTN = 64;
  __shared__ __align__(16) _Float16 As[2][BM][BK];
  __shared__ __align__(16) _Float16 Bs[2][BN][BK];
  const int tid = threadIdx.x, lane = tid & 63, wid = tid >> 6;
  const int wr = wid >> 1, wc = wid & 1;
  const int l32 = lane & 31, lh = lane >> 5;   // 32x32 frag: row/col = l32, k-group = lh
  const int chunk = gridDim.x >> 3;
  const int flat = (blockIdx.x & 7) * chunk + (blockIdx.x >> 3);
  const int bnk = flat & 7, bmk = flat >> 3;
  const size_t APS = (size_t)M_ALL * FDIM;
  const size_t WPS = (size_t)N * K;
  const int lrow8 = lane >> 3, lslot = lane & 7;

  f32x16 accA[FR][FC] = {}, accB[FR][FC] = {};

  auto stage = [&](int it) {
    #pragma unroll
    for (int q = 0; q < 8; ++q) {              // A: 2 planes x 16 row-groups / 4 waves
      int i = q * 4 + wid;
      int s = i >> 4, r0 = (i & 15) * 8;
      int row = r0 + lrow8;
      int ss = lslot ^ (row & 7);
      gl16(A + (size_t)s * APS + ((size_t)it * M_ALL + (size_t)(bmk * BM + row)) * 64 + ss * 8,
           &As[s][r0][0]);
    }
    const int k0 = it * BK;
    #pragma unroll
    for (int q = 0; q < 8; ++q) {              // B: 2 planes x 16 row-groups / 4 waves
      int i = q * 4 + wid;
      int s = i >> 4, r0 = (i & 15) * 8;
      int row = r0 + lrow8;
      int ss = lslot ^ (row & 7);
      gl16(Wp + (size_t)s * WPS + (size_t)(bnk * BN + row) * K + k0 + ss * 8, &Bs[s][r0][0]);
    }
  };

  // 32x32x16 A-frag: row = l32, k = lh*8 + j  (16B slot index = ks*2 + lh)
  auto loadA = [&](int ks, int s, int fr) -> f16x8 {
    int row = wr * WTM + fr * 32 + l32;
    int slot = ((ks << 1) | lh) ^ (row & 7);
    return *reinterpret_cast<const f16x8*>(&As[s][row][slot * 8]);
  };
  auto loadB = [&](int ks, int s, int fc) -> f16x8 {
    int row = wc * WTN + fc * 32 + l32;
    int slot = ((ks << 1) | lh) ^ (row & 7);
    return *reinterpret_cast<const f16x8*>(&Bs[s][row][slot * 8]);
  };

  auto mfma3 = [&](int ks) {
    f16x8 af[2][FR], bf[2][FC];
    #pragma unroll
    for (int s = 0; s < 2; ++s) {
      #pragma unroll
      for (int fr = 0; fr < FR; ++fr) af[s][fr] = loadA(ks, s, fr);
      #pragma unroll
      for (int fc = 0; fc < FC; ++fc) bf[s][fc] = loadB(ks, s, fc);
    }
    #pragma unroll
    for (int fr = 0; fr < FR; ++fr)
      #pragma unroll
      for (int fc = 0; fc < FC; ++fc) {
        accA[fr][fc] = __builtin_amdgcn_mfma_f32_32x32x16_f16(af[0][fr], bf[0][fc], accA[fr][fc], 0, 0, 0);
        accB[fr][fc] = __builtin_amdgcn_mfma_f32_32x32x16_f16(af[0][fr], bf[1][fc], accB[fr][fc], 0, 0, 0);
        accB[fr][fc] = __builtin_amdgcn_mfma_f32_32x32x16_f16(af[1][fr], bf[0][fc], accB[fr][fc], 0, 0, 0);
      }
  };

  stage(0);
  __syncthreads();
  constexpr int NK = K / BK;
  for (int it = 0; it < NK; ++it) {
    mfma3(0);
    mfma3(1);
    // second half: read frags, then barrier + stage next + MFMA (r11 control flow)
    {
      f16x8 af2[2][2][FR], bf2[2][2][FC];
      #pragma unroll
      for (int ks = 0; ks < 2; ++ks)
        #pragma unroll
        for (int s = 0; s < 2; ++s) {
          #pragma unroll
          for (int fr = 0; fr < FR; ++fr) af2[ks][s][fr] = loadA(2 + ks, s, fr);
          #pragma unroll
          for (int fc = 0; fc < FC; ++fc) bf2[ks][s][fc] = loadB(2 + ks, s, fc);
        }
      __syncthreads();
      if (it + 1 < NK) stage(it + 1);
      #pragma unroll
      for (int ks = 0; ks < 2; ++ks)
        #pragma unroll
        for (int fr = 0; fr < FR; ++fr)
          #pragma unroll
          for (int fc = 0; fc < FC; ++fc) {
            accA[fr][fc] = __builtin_amdgcn_mfma_f32_32x32x16_f16(af2[ks][0][fr], bf2[ks][0][fc], accA[fr][fc], 0, 0, 0);
            accB[fr][fc] = __builtin_amdgcn_mfma_f32_32x32x16_f16(af2[ks][0][fr], bf2[ks][1][fc], accB[fr][fc], 0, 0, 0);
            accB[fr][fc] = __builtin_amdgcn_mfma_f32_32x32x16_f16(af2[ks][1][fr], bf2[ks][0][fc], accB[fr][fc], 0, 0, 0);
          }
      __syncthreads();
    }
  }

  // epilogue: C/D layout col=lane&31, row=(reg&3)+8*(reg>>2)+4*(lane>>5) (m74/m101-verified)
  #pragma unroll
  for (int fc = 0; fc < FC; ++fc) {
    const int n = bnk * BN + wc * WTN + fc * 32 + l32;
    const float eb = e1[n], sn = s1[n];
    #pragma unroll
    for (int fr = 0; fr < FR; ++fr) {
      const int rbase = bmk * BM + wr * WTM + fr * 32 + 4 * lh;
      #pragma unroll
      for (int reg = 0; reg < 16; ++reg) {
        const int row = rbase + (reg & 3) + 8 * (reg >> 2);
        cOut[(size_t)row * N + n] =
            sn * (accA[fr][fc][reg] + 0.000244140625f * accB[fr][fc][reg]) + eb;
      }
    }
  }
}

// Big GEMM2/3: i8 spikes (K-TILED [K/128][M_ALL][128]) x 4 i8 digit planes -> c fp32.
// BM=128 block, 4 waves, wave tile 64 x (BN/2).  (round-11 verified config)
template<int BM, int BN, int MINW>
__global__ __launch_bounds__(256, MINW)
void gSc_kernel(const signed char* __restrict__ A, const signed char* __restrict__ Wq,
                const float* __restrict__ qs, const float* __restrict__ eb_,
                float* __restrict__ cOut, const int N, const int K)
{
  constexpr int BKI = 128;
  constexpr int WTM = BM / 2, WTN = BN / 2, FR = WTM / 16, FC = WTN / 16;
  constexpr int RA = BM / 8, RB = BN / 8;
  __shared__ __align__(16) signed char As[BM][BKI];
  __shared__ __align__(16) signed char Bs[4][BN][BKI];
  const int tid = threadIdx.x, lane = tid & 63, wid = tid >> 6;
  const int wr = wid >> 1, wc = wid & 1;
  const int l16 = lane & 15, lq = lane >> 4;
  const int chunk = gridDim.x >> 3;
  const int flat = (blockIdx.x & 7) * chunk + (blockIdx.x >> 3);
  const int bnk = flat & 7, bmk = flat >> 3;
  const size_t WPS = (size_t)N * K;
  const int lrow8 = lane >> 3, lslot = lane & 7;

  i32x4 acc[4][FR][FC] = {};

  auto stage = [&](int it) {
    #pragma unroll
    for (int q = 0; q < RA / 4; ++q) {
      int i = q * 4 + wid;
      int r0 = i * 8, row = r0 + lrow8;
      int ss = lslot ^ (row & 7);
      gl16(A + ((size_t)it * M_ALL + (size_t)(bmk * BM + row)) * BKI + ss * 16, &As[r0][0]);
    }
    const int k0 = it * BKI;
    #pragma unroll
    for (int q = 0; q < RB; ++q) {
      int i = q * 4 + wid;
      int s = i / RB, r0 = (i % RB) * 8, row = r0 + lrow8;
      int ss = lslot ^ (row & 7);
      gl16(Wq + (size_t)s * WPS + (size_t)(bnk * BN + row) * K + k0 + ss * 16, &Bs[s][r0][0]);
    }
  };

  auto loadA = [&](int kh, int fr) -> i32x4 {
    int row = wr * WTM + fr * 16 + l16;
    int slot = ((kh << 2) | lq) ^ (row & 7);
    return *reinterpret_cast<const i32x4*>(&As[row][slot * 16]);
  };
  auto loadB = [&](int kh, int s, int fc) -> i32x4 {
    int row = wc * WTN + fc * 16 + l16;
    int slot = ((kh << 2) | lq) ^ (row & 7);
    return *reinterpret_cast<const i32x4*>(&Bs[s][row][slot * 16]);
  };

  stage(0);
  __syncthreads();
  const int NK = K / BKI;
  for (int it = 0; it < NK; ++it) {
    {
      i32x4 av[FR], bv[4][FC];
      #pragma unroll
      for (int fr = 0; fr < FR; ++fr) av[fr] = loadA(0, fr);
      #pragma unroll
      for (int s = 0; s < 4; ++s)
        #pragma unroll
        for (int fc = 0; fc < FC; ++fc) bv[s][fc] = loadB(0, s, fc);
      #pragma unroll
      for (int s = 0; s < 4; ++s)
        #pragma unroll
        for (int fr = 0; fr < FR; ++fr)
          #pragma unroll
          for (int fc = 0; fc < FC; ++fc)
            acc[s][fr][fc] = __builtin_amdgcn_mfma_i32_16x16x64_i8(av[fr], bv[s][fc], acc[s][fr][fc], 0, 0, 0);
    }
    {
      i32x4 av[FR], bv[4][FC];
      #pragma unroll
      for (int fr = 0; fr < FR; ++fr) av[fr] = loadA(1, fr);
      #pragma unroll
      for (int s = 0; s < 4; ++s)
        #pragma unroll
        for (int fc = 0; fc < FC; ++fc) bv[s][fc] = loadB(1, s, fc);
      __syncthreads();
      if (it + 1 < NK) stage(it + 1);
      #pragma unroll
      for (int s = 0; s < 4; ++s)
        #pragma unroll
        for (int fr = 0; fr < FR; ++fr)
          #pragma unroll
          for (int fc = 0; fc < FC; ++fc)
            acc[s][fr][fc] = __builtin_amdgcn_mfma_i32_16x16x64_i8(av[fr], bv[s][fc], acc[s][fr][fc], 0, 0, 0);
      __syncthreads();
    }
  }

  #pragma unroll
  for (int fc = 0; fc < FC; ++fc) {
    const int n = bnk * BN + wc * WTN + fc * 16 + l16;
    const float qv = qs[n], eb = eb_[n];
    #pragma unroll
    for (int fr = 0; fr < FR; ++fr) {
      const int row0 = bmk * BM + wr * WTM + fr * 16 + lq * 4;
      #pragma unroll
      for (int r = 0; r < 4; ++r) {
        int slo = acc[0][fr][fc][r] + (acc[1][fr][fc][r] << 7) + (acc[2][fr][fc][r] << 14);
        cOut[(size_t)(row0 + r) * N + n] =
            qv * fmaf(2097152.0f, (float)acc[3][fr][fc][r], (float)slo) + eb;
      }
    }
  }
}

// LIF scan over full T: c [T][B][H] fp32 -> z K-TILED [H/128][M_ALL][128] i8 (0/1).
__global__ void scan_lif_kernel(const float* __restrict__ c, signed char* __restrict__ z,
                                int H)
{
  const int NN = BATCH * H;
  const int i4 = (blockIdx.x * 256 + threadIdx.x) * 4;
  const int b = i4 / H, n = i4 % H;
  const size_t zb = (size_t)(n >> 7) * M_ALL;
  const int nw = n & 127;
  float4 v  = make_float4(0.f, 0.f, 0.f, 0.f);
  float4 ii = make_float4(0.f, 0.f, 0.f, 0.f);
  for (int t = 0; t < TDIM; ++t) {
    const size_t o = (size_t)t * NN + i4;
    float4 cc = *reinterpret_cast<const float4*>(&c[o]);
    float4 zz;
    lif_update(cc.x, v.x, ii.x, zz.x);
    lif_update(cc.y, v.y, ii.y, zz.y);
    lif_update(cc.z, v.z, ii.z, zz.z);
    lif_update(cc.w, v.w, ii.w, zz.w);
    unsigned pz = (zz.x != 0.f ? 1u : 0u) | (zz.y != 0.f ? 256u : 0u)
                | (zz.z != 0.f ? 65536u : 0u) | (zz.w != 0.f ? 16777216u : 0u);
    *reinterpret_cast<unsigned*>(&z[(zb + (size_t)t * BATCH + b) * 128 + nw]) = pz;
  }
}

// Fused scan3 + output layer over full T: per wave = one batch row b; lane owns 4 of H3.
__global__ void scan3out_kernel(const float* __restrict__ c3,
                                const float* __restrict__ Wout, const float* __restrict__ bout,
                                float* __restrict__ out, W100 wts)
{
  const int lane = threadIdx.x & 63, wv = threadIdx.x >> 6;
  const int b = blockIdx.x * 4 + wv;
  const int n0 = lane * 4;
  float4 v  = make_float4(0.f, 0.f, 0.f, 0.f);
  float4 ii = make_float4(0.f, 0.f, 0.f, 0.f);
  const float4 w0 = *reinterpret_cast<const float4*>(&Wout[n0]);
  const float4 w1 = *reinterpret_cast<const float4*>(&Wout[H3 + n0]);
  const float bo0 = bout[0], bo1 = bout[1];
  float vo0 = 0.f, io0 = 0.f, vo1 = 0.f, io1 = 0.f;
  float acc0 = 0.0f, acc1 = 0.0f;
  for (int t = 0; t < TDIM; ++t) {
    const size_t o = ((size_t)t * BATCH + b) * H3 + n0;
    float4 cc = *reinterpret_cast<const float4*>(&c3[o]);
    float4 zz;
    lif_update(cc.x, v.x, ii.x, zz.x);
    lif_update(cc.y, v.y, ii.y, zz.y);
    lif_update(cc.z, v.z, ii.z, zz.z);
    lif_update(cc.w, v.w, ii.w, zz.w);
    float s0 = fmaf(zz.x, w0.x, fmaf(zz.y, w0.y, fmaf(zz.z, w0.z, zz.w * w0.w)));
    float s1 = fmaf(zz.x, w1.x, fmaf(zz.y, w1.y, fmaf(zz.z, w1.z, zz.w * w1.w)));
    #pragma unroll
    for (int m = 1; m < 64; m <<= 1) {
      s0 += __shfl_xor(s0, m);
      s1 += __shfl_xor(s1, m);
    }
    float zo0, zo1;
    lif_update(s0 + bo0, vo0, io0, zo0);
    lif_update(s1 + bo1, vo1, io1, zo1);
    acc0 += zo0 * wts.w[t];
    acc1 += zo1 * wts.w[t];
  }
  if (lane == 0) {
    const int oidx = b * ODIM;
    out[oidx]     = acc0;
    out[oidx + 1] = acc1;
  }
}

// ---------------- fp32 fallback path (round-1 kernels) ----------------
__global__ void fold1_kernel(const float* __restrict__ W1, const float* __restrict__ b1,
                             const float* __restrict__ g1, const float* __restrict__ bb1,
                             const float* __restrict__ m1, const float* __restrict__ v1,
                             const float* __restrict__ gi, const float* __restrict__ bi,
                             const float* __restrict__ mi, const float* __restrict__ vi,
                             float* __restrict__ W1f, float* __restrict__ e1) {
  const int j = blockIdx.x;
  const int tid = threadIdx.x;
  const float sg = g1[j] / sqrtf(v1[j] + 1e-5f);
  float part = 0.0f;
  for (int f = tid; f < FDIM; f += 256) {
    float si = gi[f] / sqrtf(vi[f] + 1e-5f);
    float h0 = bi[f] - mi[f] * si;
    float w  = W1[j * FDIM + f];
    part += w * h0;
    W1f[j * FDIM + f] = w * si * sg;
  }
  #pragma unroll
  for (int m = 1; m < 64; m <<= 1) part += __shfl_xor(part, m);
  __shared__ float red[4];
  if ((tid & 63) == 0) red[tid >> 6] = part;
  __syncthreads();
  if (tid == 0) {
    float d = red[0] + red[1] + red[2] + red[3];
    e1[j] = (d + b1[j] - m1[j]) * sg + bb1[j];
  }
}

__global__ void foldS_kernel(const float* __restrict__ W, const float* __restrict__ b,
                             const float* __restrict__ g, const float* __restrict__ bb,
                             const float* __restrict__ m, const float* __restrict__ v,
                             float* __restrict__ Wf, float* __restrict__ e, int K) {
  const int j = blockIdx.x;
  const float sg = g[j] / sqrtf(v[j] + 1e-5f);
  for (int k = threadIdx.x; k < K; k += 256)
    Wf[j * K + k] = W[j * K + k] * sg;
  if (threadIdx.x == 0) e[j] = (b[j] - m[j]) * sg + bb[j];
}

template<int TM, int TN, bool CONTIG>
__global__ __launch_bounds__(256, 2)
void gemm_lif_kernel(const float* __restrict__ A, size_t ars, size_t acs,
                     const float* __restrict__ W, const float* __restrict__ ebias,
                     float* __restrict__ vst, float* __restrict__ ist,
                     float* __restrict__ zout, int N, int K)
{
  constexpr int BK = 16;
  constexpr int BM = 16 * TM;
  constexpr int BN = 16 * TN;
  __shared__ float As[BK][BM];
  __shared__ float Bs[BK][BN];
  const int tid = threadIdx.x;
  const int tx = tid & 15, ty = tid >> 4;
  const int bn = blockIdx.x, bm = blockIdx.y;
  const float* Ablk = A + (size_t)bm * BM * ars;
  const float* Wblk = W + (size_t)bn * BN * (size_t)K;

  float acc[TM][TN];
  #pragma unroll
  for (int r = 0; r < TM; r++)
    #pragma unroll
    for (int c = 0; c < TN; c++) acc[r][c] = 0.0f;

  for (int k0 = 0; k0 < K; k0 += BK) {
    if (CONTIG) {
      constexpr int A4 = BM * BK / 4;
      #pragma unroll
      for (int q = 0; q < A4 / 256; q++) {
        int idx = q * 256 + tid;
        int r = idx >> 2;
        int kq = (idx & 3) << 2;
        float4 val = *reinterpret_cast<const float4*>(Ablk + (size_t)r * ars + (size_t)(k0 + kq));
        As[kq + 0][r] = val.x; As[kq + 1][r] = val.y;
        As[kq + 2][r] = val.z; As[kq + 3][r] = val.w;
      }
    } else {
      #pragma unroll
      for (int q = 0; q < BM * BK / 256; q++) {
        int idx = q * 256 + tid;
        int r = idx >> 4;
        int kk = idx & 15;
        As[kk][r] = Ablk[(size_t)r * ars + (size_t)(k0 + kk) * acs];
      }
    }
    {
      int n  = tid >> 2;
      int kq = (tid & 3) << 2;
      float4 val = *reinterpret_cast<const float4*>(Wblk + (size_t)n * K + (size_t)(k0 + kq));
      Bs[kq + 0][n] = val.x; Bs[kq + 1][n] = val.y;
      Bs[kq + 2][n] = val.z; Bs[kq + 3][n] = val.w;
    }
    __syncthreads();
    #pragma unroll
    for (int kk = 0; kk < BK; kk++) {
      float a[TM], bv[TN];
      const float4* ap = reinterpret_cast<const float4*>(&As[kk][ty * TM]);
      *reinterpret_cast<float4*>(&a[0]) = ap[0];
      if (TM == 8) *reinterpret_cast<float4*>(&a[4]) = ap[1];
      *reinterpret_cast<float4*>(&bv[0]) = *reinterpret_cast<const float4*>(&Bs[kk][tx * TN]);
      #pragma unroll
      for (int r = 0; r < TM; r++)
        #pragma unroll
        for (int c = 0; c < TN; c++)
          acc[r][c] = fmaf(a[r], bv[c], acc[r][c]);
    }
    __syncthreads();
  }

  const int n0 = bn * BN + tx * TN;
  const float4 ev = *reinterpret_cast<const float4*>(ebias + n0);
  #pragma unroll
  for (int r = 0; r < TM; r++) {
    const int brow = bm * BM + ty * TM + r;
    const size_t idx = (size_t)brow * N + n0;
    float c0 = acc[r][0] + ev.x;
    float c1 = acc[r][1] + ev.y;
    float c2 = acc[r][2] + ev.z;
    float c3 = acc[r][3] + ev.w;
    float4 vv = *reinterpret_cast<const float4*>(vst + idx);
    float4 ii = *reinterpret_cast<const float4*>(ist + idx);
    float4 zz;
    lif_update(c0, vv.x, ii.x, zz.x);
    lif_update(c1, vv.y, ii.y, zz.y);
    lif_update(c2, vv.z, ii.z, zz.z);
    lif_update(c3, vv.w, ii.w, zz.w);
    *reinterpret_cast<float4*>(zout + idx) = zz;
    *reinterpret_cast<float4*>(vst  + idx) = vv;
    *reinterpret_cast<float4*>(ist  + idx) = ii;
  }
}

__global__ void out_kernel(const float* __restrict__ z3, const float* __restrict__ Wout,
                           const float* __restrict__ bout, float* __restrict__ vo,
                           float* __restrict__ io, float* __restrict__ acc, float wt) {
  const int idx = blockIdx.x * 256 + threadIdx.x;
  if (idx >= BATCH * ODIM) return;
  const int b = idx >> 1, o = idx & 1;
  const float4* zr = reinterpret_cast<const float4*>(z3 + (size_t)b * H3);
  const float4* wr = reinterpret_cast<const float4*>(Wout + o * H3);
  float s = 0.0f;
  #pragma unroll 4
  for (int k = 0; k < H3 / 4; k++) {
    float4 zv = zr[k], wv = wr[k];
    s += zv.x * wv.x + zv.y * wv.y + zv.z * wv.z + zv.w * wv.w;
  }
  float cin = s + bout[o];
  float v = vo[idx], i = io[idx], z;
  lif_update(cin, v, i, z);
  vo[idx] = v; io[idx] = i;
  acc[idx] += z * wt;
}

extern "C" void kernel_launch(void* const* d_in, const int* in_sizes, int n_in,
                              void* d_out, int out_size, void* d_ws, size_t ws_size,
                              hipStream_t stream) {
  const float* x     = (const float*)d_in[0];
  const float* bni_g = (const float*)d_in[1];
  const float* bni_b = (const float*)d_in[2];
  const float* bni_m = (const float*)d_in[3];
  const float* bni_v = (const float*)d_in[4];
  const float* W1    = (const float*)d_in[5];
  const float* b1    = (const float*)d_in[6];
  const float* bn1_g = (const float*)d_in[7];
  const float* bn1_b = (const float*)d_in[8];
  const float* bn1_m = (const float*)d_in[9];
  const float* bn1_v = (const float*)d_in[10];
  const float* W2    = (const float*)d_in[11];
  const float* b2    = (const float*)d_in[12];
  const float* bn2_g = (const float*)d_in[13];
  const float* bn2_b = (const float*)d_in[14];
  const float* bn2_m = (const float*)d_in[15];
  const float* bn2_v = (const float*)d_in[16];
  const float* W3    = (const float*)d_in[17];
  const float* b3    = (const float*)d_in[18];
  const float* bn3_g = (const float*)d_in[19];
  const float* bn3_b = (const float*)d_in[20];
  const float* bn3_m = (const float*)d_in[21];
  const float* bn3_v = (const float*)d_in[22];
  const float* Wout  = (const float*)d_in[23];
  const float* bout  = (const float*)d_in[24];
  float* out = (float*)d_out;

  float* ws = (float*)d_ws;
  size_t off = 0;
  auto alloc = [&](size_t n) { float* p = ws + off; off += n; return p; };

  // ---- single-chunk big-GEMM path with region aliasing ----
  float* e1 = alloc(H1);
  float* e2 = alloc(H2);
  float* e3 = alloc(H3);
  float* s1 = alloc(H1);
  float* q2 = alloc(H2);
  float* q3 = alloc(H3);
  unsigned char* base = (unsigned char*)(ws + off);
  size_t boff = 0;
  auto carve = [&](size_t bytes) {
    void* p = base + boff;
    boff += (bytes + 255) & ~(size_t)255;
    return p;
  };
  _Float16* W1p   = (_Float16*)carve((size_t)2 * H1 * FDIM * 2);
  signed char* W2q = (signed char*)carve((size_t)4 * H2 * H1);
  signed char* W3q = (signed char*)carve((size_t)4 * H3 * H2);
  signed char* z1  = (signed char*)carve((size_t)M_ALL * H1);
  signed char* z2  = (signed char*)carve((size_t)M_ALL * H2);
  void* regionA = carve((size_t)2 * M_ALL * FDIM * 2);   // Xp (fp16 2-plane) / c2 (fp32)
  void* regionB = carve((size_t)M_ALL * H1 * 4);         // c1 (fp32) / c3 (fp32)
  _Float16* Xp = (_Float16*)regionA;
  float* c2    = (float*)regionA;
  float* c1    = (float*)regionB;
  float* c3    = (float*)regionB;
  const size_t needed = off * sizeof(float) + boff;

  if (ws_size >= needed) {
    // folds (independent)
    fold1_f16<<<H1, 256, 0, stream>>>(W1, b1, bn1_g, bn1_b, bn1_m, bn1_v,
                                      bni_g, bni_b, bni_m, bni_v, W1p, s1, e1);
    foldS_i8<<<H2, 256, 0, stream>>>(W2, b2, bn2_g, bn2_b, bn2_m, bn2_v, W2q, q2, e2, H2, H1);
    foldS_i8<<<H3, 256, 0, stream>>>(W3, b3, bn3_g, bn3_b, bn3_m, bn3_v, W3q, q3, e3, H3, H2);

    // serial layer chain over the full T at once
    tchunk_kernel<<<dim3(FDIM / 64, BATCH), 256, 0, stream>>>(x, Xp);
    g1c_kernel<<<(H1 / 128) * (M_ALL / 128), 256, 0, stream>>>(Xp, W1p, s1, e1, c1);
    scan_lif_kernel<<<BATCH * H1 / 1024, 256, 0, stream>>>(c1, z1, H1);
    gSc_kernel<128, 64, 2><<<(H2 / 64) * (M_ALL / 128), 256, 0, stream>>>(z1, W2q, q2, e2, c2, H2, H1);
    scan_lif_kernel<<<BATCH * H2 / 1024, 256, 0, stream>>>(c2, z2, H2);
    gSc_kernel<128, 32, 3><<<(H3 / 32) * (M_ALL / 128), 256, 0, stream>>>(z2, W3q, q3, e3, c3, H3, H2);
    W100 wts;
    for (int t = 0; t < TDIM; ++t)
      wts.w[t] = (float)std::pow(0.995, (double)(TDIM - 1 - t));
    scan3out_kernel<<<BATCH / 4, 256, 0, stream>>>(c3, Wout, bout, out, wts);
    return;
  }

  // ---- fp32 fallback (strided GEMM1, no transpose) ----
  off = 0;
  float* W1f = alloc((size_t)H1 * FDIM);
  float* W2f = alloc((size_t)H2 * H1);
  float* W3f = alloc((size_t)H3 * H2);
  float* fe1 = alloc(H1);
  float* fe2 = alloc(H2);
  float* fe3 = alloc(H3);
  float* fv1 = alloc((size_t)BATCH * H1);
  float* fi1 = alloc((size_t)BATCH * H1);
  float* fv2 = alloc((size_t)BATCH * H2);
  float* fi2 = alloc((size_t)BATCH * H2);
  float* fv3 = alloc((size_t)BATCH * H3);
  float* fi3 = alloc((size_t)BATCH * H3);
  float* fvo = alloc((size_t)BATCH * ODIM);
  float* fio = alloc((size_t)BATCH * ODIM);
  float* fz1 = alloc((size_t)BATCH * H1);
  float* fz2 = alloc((size_t)BATCH * H2);
  float* fz3 = alloc((size_t)BATCH * H3);

  const int nstate = BATCH * (2 * H1 + 2 * H2 + 2 * H3 + 2 * ODIM);
  zero_kernel<<<2048, 256, 0, stream>>>(fv1, nstate);
  zero_kernel<<<16, 256, 0, stream>>>(out, BATCH * ODIM);

  fold1_kernel<<<H1, 256, 0, stream>>>(W1, b1, bn1_g, bn1_b, bn1_m, bn1_v,
                                       bni_g, bni_b, bni_m, bni_v, W1f, fe1);
  foldS_kernel<<<H2, 256, 0, stream>>>(W2, b2, bn2_g, bn2_b, bn2_m, bn2_v, W2f, fe2, H1);
  foldS_kernel<<<H3, 256, 0, stream>>>(W3, b3, bn3_g, bn3_b, bn3_m, bn3_v, W3f, fe3, H2);

  const dim3 fg1(H1 / 64, BATCH / 128);
  const dim3 fg2(H2 / 64, BATCH / 64);
  const dim3 fg3(H3 / 64, BATCH / 64);

  for (int t = 0; t < TDIM; t++) {
    gemm_lif_kernel<8, 4, false><<<fg1, 256, 0, stream>>>(
        x + t, (size_t)FDIM * TDIM, TDIM, W1f, fe1, fv1, fi1, fz1, H1, FDIM);
    gemm_lif_kernel<4, 4, true><<<fg2, 256, 0, stream>>>(fz1, H1, 1, W2f, fe2, fv2, fi2, fz2, H2, H1);
    gemm_lif_kernel<4, 4, true><<<fg3, 256, 0, stream>>>(fz2, H2, 1, W3f, fe3, fv3, fi3, fz3, H3, H2);
    float wt = (float)std::pow(0.995, (double)(TDIM - 1 - t));
    out_kernel<<<BATCH * ODIM / 256, 256, 0, stream>>>(fz3, Wout, bout, fvo, fio, out, wt);
  }
}

// Round 15
// 1723.704 us; speedup vs baseline: 2.2288x; 1.0279x over previous
//
#include <hip/hip_runtime.h>
#include <cmath>

#define BATCH 2048
#define FDIM  512
#define TDIM  100
#define H1    1024
#define H2    512
#define H3    256
#define ODIM  2
#define M_ALL (TDIM * BATCH)   // 204800 GEMM rows

typedef __attribute__((ext_vector_type(8))) _Float16 f16x8;
typedef __attribute__((ext_vector_type(4))) _Float16 f16x4;
typedef __attribute__((ext_vector_type(4))) float f32x4;
typedef __attribute__((ext_vector_type(4))) int i32x4;

struct W100 { float w[TDIM]; };

__device__ __forceinline__ void gl16(const void* g, void* l) {
  __builtin_amdgcn_global_load_lds(
      (const __attribute__((address_space(1))) unsigned int*)g,
      (__attribute__((address_space(3))) unsigned int*)l, 16, 0, 0);
}

// LIF update exactly mirroring the reference order
__device__ __forceinline__ void lif_update(float c, float& v, float& i, float& z) {
  float vd = v + 0.1f * (i - v);
  float id = 0.8f * i;
  z = (vd - 1.0f) > 0.0f ? 1.0f : 0.0f;
  v = (z != 0.0f) ? 0.0f : vd;
  i = id + c;
}

__global__ void zero_kernel(float* __restrict__ p, int n) {
  for (int i = blockIdx.x * blockDim.x + threadIdx.x; i < n; i += gridDim.x * blockDim.x)
    p[i] = 0.0f;
}

// Full-T transpose+split: x (B,F,T) -> xp K-TILED [2][FDIM/64][M_ALL][64] fp16 planes.
// 512 threads/block (loop-stride only change vs r11).
__global__ void tchunk_kernel(const float* __restrict__ x, _Float16* __restrict__ xp) {
  __shared__ float tile[64][105];
  const int kt = blockIdx.x;
  const int f0 = kt * 64;
  const int b  = blockIdx.y;
  const int tid = threadIdx.x;
  const size_t xb = (size_t)b * FDIM * TDIM;
  for (int idx = tid; idx < 1600; idx += 512) {       // 64 rows x 25 float4
    const int f = idx / 25, q = idx % 25;
    float4 v = *reinterpret_cast<const float4*>(&x[xb + (size_t)(f0 + f) * TDIM + q * 4]);
    tile[f][q * 4 + 0] = v.x; tile[f][q * 4 + 1] = v.y;
    tile[f][q * 4 + 2] = v.z; tile[f][q * 4 + 3] = v.w;
  }
  __syncthreads();
  const size_t PS = (size_t)M_ALL * FDIM;
  for (int idx = tid; idx < 1600; idx += 512) {       // 100 t x 16 f-quads
    const int t = idx >> 4, fq = idx & 15;
    f16x4 h, m;
    #pragma unroll
    for (int j = 0; j < 4; ++j) {
      float xa = tile[fq * 4 + j][t] * 64.0f;
      _Float16 hh = (_Float16)xa;
      float rm = (xa - (float)hh) * 4096.0f;
      h[j] = hh;
      m[j] = (_Float16)rm;
    }
    const size_t o = ((size_t)kt * M_ALL + (size_t)t * BATCH + b) * 64 + fq * 4;
    *reinterpret_cast<f16x4*>(&xp[o])      = h;
    *reinterpret_cast<f16x4*>(&xp[PS + o]) = m;
  }
}

// Layer-1 fold: BN scales folded, then per-row fp16 2-plane split with per-row pow2 scale.
__global__ void fold1_f16(const float* __restrict__ W1, const float* __restrict__ b1,
                          const float* __restrict__ g1, const float* __restrict__ bb1,
                          const float* __restrict__ m1, const float* __restrict__ v1,
                          const float* __restrict__ gi, const float* __restrict__ bi,
                          const float* __restrict__ mi, const float* __restrict__ vi,
                          _Float16* __restrict__ W1p, float* __restrict__ s1,
                          float* __restrict__ e1) {
  __shared__ float swf[FDIM];
  __shared__ float red[8];
  __shared__ float bsw[1];
  const int j = blockIdx.x, tid = threadIdx.x;
  const float sg = g1[j] / sqrtf(v1[j] + 1e-5f);
  float part = 0.0f, pmax = 0.0f;
  for (int f = tid; f < FDIM; f += 256) {
    float si = gi[f] / sqrtf(vi[f] + 1e-5f);
    float h0 = bi[f] - mi[f] * si;
    float w  = W1[j * FDIM + f];
    part += w * h0;
    float wf = w * si * sg;
    swf[f] = wf;
    pmax = fmaxf(pmax, fabsf(wf));
  }
  #pragma unroll
  for (int s = 1; s < 64; s <<= 1) {
    part += __shfl_xor(part, s);
    pmax = fmaxf(pmax, __shfl_xor(pmax, s));
  }
  if ((tid & 63) == 0) { red[tid >> 6] = part; red[4 + (tid >> 6)] = pmax; }
  __syncthreads();
  if (tid == 0) {
    float d = red[0] + red[1] + red[2] + red[3];
    e1[j] = (d + b1[j] - m1[j]) * sg + bb1[j];
    float mx = fmaxf(fmaxf(red[4], red[5]), fmaxf(red[6], red[7]));
    int e = 0;
    if (mx > 0.0f) frexpf(mx, &e);
    s1[j] = exp2f((float)(e - 11));       // combine scale: 2^(e-5) * 2^-6 (A-side 64)
    bsw[0] = exp2f((float)(5 - e));       // |wf * SW| <= 32
  }
  __syncthreads();
  const float SW = bsw[0];
  const size_t PS = (size_t)H1 * FDIM;
  for (int f = tid; f < FDIM; f += 256) {
    float wa = swf[f] * SW;
    _Float16 wh = (_Float16)wa;
    float r = (wa - (float)wh) * 4096.0f;
    W1p[(size_t)j * FDIM + f]      = wh;
    W1p[PS + (size_t)j * FDIM + f] = (_Float16)r;
  }
}

// Layers 2/3 fold: per-row 28-bit integer quantization into 4 signed-7-bit i8 digit planes.
__global__ void foldS_i8(const float* __restrict__ W, const float* __restrict__ b,
                         const float* __restrict__ g, const float* __restrict__ bb,
                         const float* __restrict__ m, const float* __restrict__ v,
                         signed char* __restrict__ Wq, float* __restrict__ qs,
                         float* __restrict__ e, int N, int K) {
  __shared__ float swf[1024];
  __shared__ float red[4];
  __shared__ int bse[1];
  const int j = blockIdx.x, tid = threadIdx.x;
  const float sg = g[j] / sqrtf(v[j] + 1e-5f);
  float pmax = 0.0f;
  for (int k = tid; k < K; k += 256) {
    float wf = W[(size_t)j * K + k] * sg;
    swf[k] = wf;
    pmax = fmaxf(pmax, fabsf(wf));
  }
  #pragma unroll
  for (int s = 1; s < 64; s <<= 1) pmax = fmaxf(pmax, __shfl_xor(pmax, s));
  if ((tid & 63) == 0) red[tid >> 6] = pmax;
  __syncthreads();
  if (tid == 0) {
    float mx = fmaxf(fmaxf(red[0], red[1]), fmaxf(red[2], red[3]));
    int ee = 0;
    if (mx > 0.0f) frexpf(mx, &ee);
    qs[j] = exp2f((float)(ee - 27));
    bse[0] = 27 - ee;
    e[j] = (b[j] - m[j]) * sg + bb[j];
  }
  __syncthreads();
  const double sc = ldexp(1.0, bse[0]);
  const size_t PS = (size_t)N * K;
  for (int k = tid; k < K; k += 256) {
    long D = llround((double)swf[k] * sc);   // |D| <= 2^27
    #pragma unroll
    for (int p = 0; p < 3; p++) {
      int d = (int)(D & 127);
      if (d >= 64) d -= 128;
      Wq[(size_t)p * PS + (size_t)j * K + k] = (signed char)d;
      D = (D - d) >> 7;
    }
    Wq[3 * PS + (size_t)j * K + k] = (signed char)D;  // |D| <= 64
  }
}

// Big GEMM1 (M_ALL x H1 x FDIM), fp16 2-plane x 2-plane (3 pairs) -> c1 fp32.
// 128x128 block, 4 waves, wave tile 64x64 (FR=FC=4), 16x16x32 MFMA. (r11 verified: 665us, 0 conflicts)
__global__ __launch_bounds__(256, 2)
void g1c_kernel(const _Float16* __restrict__ A, const _Float16* __restrict__ Wp,
                const float* __restrict__ s1, const float* __restrict__ e1,
                float* __restrict__ cOut)
{
  constexpr int BM = 128, BN = 128, K = FDIM, N = H1, BK = 64;
  constexpr int FR = 4, FC = 4, WTM = 64, WTN = 64;
  __shared__ __align__(16) _Float16 As[2][BM][BK];
  __shared__ __align__(16) _Float16 Bs[2][BN][BK];
  const int tid = threadIdx.x, lane = tid & 63, wid = tid >> 6;
  const int wr = wid >> 1, wc = wid & 1;
  const int l16 = lane & 15, lq = lane >> 4;
  const int chunk = gridDim.x >> 3;
  const int flat = (blockIdx.x & 7) * chunk + (blockIdx.x >> 3);
  const int bnk = flat & 7, bmk = flat >> 3;
  const size_t APS = (size_t)M_ALL * FDIM;
  const size_t WPS = (size_t)N * K;
  const int lrow8 = lane >> 3, lslot = lane & 7;

  f32x4 accA[FR][FC] = {}, accB[FR][FC] = {};

  auto stage = [&](int it) {
    #pragma unroll
    for (int q = 0; q < 8; ++q) {              // A: 2 planes x 16 row-groups / 4 waves
      int i = q * 4 + wid;
      int s = i >> 4, r0 = (i & 15) * 8;
      int row = r0 + lrow8;
      int ss = lslot ^ (row & 7);
      gl16(A + (size_t)s * APS + ((size_t)it * M_ALL + (size_t)(bmk * BM + row)) * 64 + ss * 8,
           &As[s][r0][0]);
    }
    const int k0 = it * BK;
    #pragma unroll
    for (int q = 0; q < 8; ++q) {              // B: 2 planes x 16 row-groups / 4 waves
      int i = q * 4 + wid;
      int s = i >> 4, r0 = (i & 15) * 8;
      int row = r0 + lrow8;
      int ss = lslot ^ (row & 7);
      gl16(Wp + (size_t)s * WPS + (size_t)(bnk * BN + row) * K + k0 + ss * 8, &Bs[s][r0][0]);
    }
  };

  auto loadA = [&](int kh, int s, int fr) -> f16x8 {
    int row = wr * WTM + fr * 16 + l16;
    int slot = ((kh << 2) | lq) ^ (row & 7);
    return *reinterpret_cast<const f16x8*>(&As[s][row][slot * 8]);
  };
  auto loadB = [&](int kh, int s, int fc) -> f16x8 {
    int row = wc * WTN + fc * 16 + l16;
    int slot = ((kh << 2) | lq) ^ (row & 7);
    return *reinterpret_cast<const f16x8*>(&Bs[s][row][slot * 8]);
  };

  stage(0);
  __syncthreads();
  constexpr int NK = K / BK;
  for (int it = 0; it < NK; ++it) {
    {
      f16x8 af[2][FR], bf[2][FC];
      #pragma unroll
      for (int s = 0; s < 2; ++s) {
        #pragma unroll
        for (int fr = 0; fr < FR; ++fr) af[s][fr] = loadA(0, s, fr);
        #pragma unroll
        for (int fc = 0; fc < FC; ++fc) bf[s][fc] = loadB(0, s, fc);
      }
      #pragma unroll
      for (int fr = 0; fr < FR; ++fr)
        #pragma unroll
        for (int fc = 0; fc < FC; ++fc) {
          accA[fr][fc] = __builtin_amdgcn_mfma_f32_16x16x32_f16(af[0][fr], bf[0][fc], accA[fr][fc], 0, 0, 0);
          accB[fr][fc] = __builtin_amdgcn_mfma_f32_16x16x32_f16(af[0][fr], bf[1][fc], accB[fr][fc], 0, 0, 0);
          accB[fr][fc] = __builtin_amdgcn_mfma_f32_16x16x32_f16(af[1][fr], bf[0][fc], accB[fr][fc], 0, 0, 0);
        }
    }
    {
      f16x8 af[2][FR], bf[2][FC];
      #pragma unroll
      for (int s = 0; s < 2; ++s) {
        #pragma unroll
        for (int fr = 0; fr < FR; ++fr) af[s][fr] = loadA(1, s, fr);
        #pragma unroll
        for (int fc = 0; fc < FC; ++fc) bf[s][fc] = loadB(1, s, fc);
      }
      __syncthreads();
      if (it + 1 < NK) stage(it + 1);
      #pragma unroll
      for (int fr = 0; fr < FR; ++fr)
        #pragma unroll
        for (int fc = 0; fc < FC; ++fc) {
          accA[fr][fc] = __builtin_amdgcn_mfma_f32_16x16x32_f16(af[0][fr], bf[0][fc], accA[fr][fc], 0, 0, 0);
          accB[fr][fc] = __builtin_amdgcn_mfma_f32_16x16x32_f16(af[0][fr], bf[1][fc], accB[fr][fc], 0, 0, 0);
          accB[fr][fc] = __builtin_amdgcn_mfma_f32_16x16x32_f16(af[1][fr], bf[0][fc], accB[fr][fc], 0, 0, 0);
        }
      __syncthreads();
    }
  }

  #pragma unroll
  for (int fc = 0; fc < FC; ++fc) {
    const int n = bnk * BN + wc * WTN + fc * 16 + l16;
    const float eb = e1[n], sn = s1[n];
    #pragma unroll
    for (int fr = 0; fr < FR; ++fr) {
      const int row0 = bmk * BM + wr * WTM + fr * 16 + lq * 4;
      #pragma unroll
      for (int r = 0; r < 4; ++r)
        cOut[(size_t)(row0 + r) * N + n] =
            sn * (accA[fr][fc][r] + 0.000244140625f * accB[fr][fc][r]) + eb;
    }
  }
}

// Big GEMM2/3: i8 spikes (K-TILED [K/128][M_ALL][128]) x 4 i8 digit planes -> c fp32.
// BM=128 block, 4 waves, wave tile 64 x (BN/2).  (r11 verified config)
template<int BM, int BN, int MINW>
__global__ __launch_bounds__(256, MINW)
void gSc_kernel(const signed char* __restrict__ A, const signed char* __restrict__ Wq,
                const float* __restrict__ qs, const float* __restrict__ eb_,
                float* __restrict__ cOut, const int N, const int K)
{
  constexpr int BKI = 128;
  constexpr int WTM = BM / 2, WTN = BN / 2, FR = WTM / 16, FC = WTN / 16;
  constexpr int RA = BM / 8, RB = BN / 8;
  __shared__ __align__(16) signed char As[BM][BKI];
  __shared__ __align__(16) signed char Bs[4][BN][BKI];
  const int tid = threadIdx.x, lane = tid & 63, wid = tid >> 6;
  const int wr = wid >> 1, wc = wid & 1;
  const int l16 = lane & 15, lq = lane >> 4;
  const int chunk = gridDim.x >> 3;
  const int flat = (blockIdx.x & 7) * chunk + (blockIdx.x >> 3);
  const int bnk = flat & 7, bmk = flat >> 3;
  const size_t WPS = (size_t)N * K;
  const int lrow8 = lane >> 3, lslot = lane & 7;

  i32x4 acc[4][FR][FC] = {};

  auto stage = [&](int it) {
    #pragma unroll
    for (int q = 0; q < RA / 4; ++q) {
      int i = q * 4 + wid;
      int r0 = i * 8, row = r0 + lrow8;
      int ss = lslot ^ (row & 7);
      gl16(A + ((size_t)it * M_ALL + (size_t)(bmk * BM + row)) * BKI + ss * 16, &As[r0][0]);
    }
    const int k0 = it * BKI;
    #pragma unroll
    for (int q = 0; q < RB; ++q) {
      int i = q * 4 + wid;
      int s = i / RB, r0 = (i % RB) * 8, row = r0 + lrow8;
      int ss = lslot ^ (row & 7);
      gl16(Wq + (size_t)s * WPS + (size_t)(bnk * BN + row) * K + k0 + ss * 16, &Bs[s][r0][0]);
    }
  };

  auto loadA = [&](int kh, int fr) -> i32x4 {
    int row = wr * WTM + fr * 16 + l16;
    int slot = ((kh << 2) | lq) ^ (row & 7);
    return *reinterpret_cast<const i32x4*>(&As[row][slot * 16]);
  };
  auto loadB = [&](int kh, int s, int fc) -> i32x4 {
    int row = wc * WTN + fc * 16 + l16;
    int slot = ((kh << 2) | lq) ^ (row & 7);
    return *reinterpret_cast<const i32x4*>(&Bs[s][row][slot * 16]);
  };

  stage(0);
  __syncthreads();
  const int NK = K / BKI;
  for (int it = 0; it < NK; ++it) {
    {
      i32x4 av[FR], bv[4][FC];
      #pragma unroll
      for (int fr = 0; fr < FR; ++fr) av[fr] = loadA(0, fr);
      #pragma unroll
      for (int s = 0; s < 4; ++s)
        #pragma unroll
        for (int fc = 0; fc < FC; ++fc) bv[s][fc] = loadB(0, s, fc);
      #pragma unroll
      for (int s = 0; s < 4; ++s)
        #pragma unroll
        for (int fr = 0; fr < FR; ++fr)
          #pragma unroll
          for (int fc = 0; fc < FC; ++fc)
            acc[s][fr][fc] = __builtin_amdgcn_mfma_i32_16x16x64_i8(av[fr], bv[s][fc], acc[s][fr][fc], 0, 0, 0);
    }
    {
      i32x4 av[FR], bv[4][FC];
      #pragma unroll
      for (int fr = 0; fr < FR; ++fr) av[fr] = loadA(1, fr);
      #pragma unroll
      for (int s = 0; s < 4; ++s)
        #pragma unroll
        for (int fc = 0; fc < FC; ++fc) bv[s][fc] = loadB(1, s, fc);
      __syncthreads();
      if (it + 1 < NK) stage(it + 1);
      #pragma unroll
      for (int s = 0; s < 4; ++s)
        #pragma unroll
        for (int fr = 0; fr < FR; ++fr)
          #pragma unroll
          for (int fc = 0; fc < FC; ++fc)
            acc[s][fr][fc] = __builtin_amdgcn_mfma_i32_16x16x64_i8(av[fr], bv[s][fc], acc[s][fr][fc], 0, 0, 0);
      __syncthreads();
    }
  }

  #pragma unroll
  for (int fc = 0; fc < FC; ++fc) {
    const int n = bnk * BN + wc * WTN + fc * 16 + l16;
    const float qv = qs[n], eb = eb_[n];
    #pragma unroll
    for (int fr = 0; fr < FR; ++fr) {
      const int row0 = bmk * BM + wr * WTM + fr * 16 + lq * 4;
      #pragma unroll
      for (int r = 0; r < 4; ++r) {
        int slo = acc[0][fr][fc][r] + (acc[1][fr][fc][r] << 7) + (acc[2][fr][fc][r] << 14);
        cOut[(size_t)(row0 + r) * N + n] =
            qv * fmaf(2097152.0f, (float)acc[3][fr][fc][r], (float)slo) + eb;
      }
    }
  }
}

// LIF scan over full T: c [T][B][H] fp32 -> z K-TILED [H/128][M_ALL][128] i8 (0/1).
__global__ void scan_lif_kernel(const float* __restrict__ c, signed char* __restrict__ z,
                                int H)
{
  const int NN = BATCH * H;
  const int i4 = (blockIdx.x * 256 + threadIdx.x) * 4;
  const int b = i4 / H, n = i4 % H;
  const size_t zb = (size_t)(n >> 7) * M_ALL;
  const int nw = n & 127;
  float4 v  = make_float4(0.f, 0.f, 0.f, 0.f);
  float4 ii = make_float4(0.f, 0.f, 0.f, 0.f);
  for (int t = 0; t < TDIM; ++t) {
    const size_t o = (size_t)t * NN + i4;
    float4 cc = *reinterpret_cast<const float4*>(&c[o]);
    float4 zz;
    lif_update(cc.x, v.x, ii.x, zz.x);
    lif_update(cc.y, v.y, ii.y, zz.y);
    lif_update(cc.z, v.z, ii.z, zz.z);
    lif_update(cc.w, v.w, ii.w, zz.w);
    unsigned pz = (zz.x != 0.f ? 1u : 0u) | (zz.y != 0.f ? 256u : 0u)
                | (zz.z != 0.f ? 65536u : 0u) | (zz.w != 0.f ? 16777216u : 0u);
    *reinterpret_cast<unsigned*>(&z[(zb + (size_t)t * BATCH + b) * 128 + nw]) = pz;
  }
}

// Fused scan3 + output layer over full T: per wave = one batch row b; lane owns 4 of H3.
__global__ void scan3out_kernel(const float* __restrict__ c3,
                                const float* __restrict__ Wout, const float* __restrict__ bout,
                                float* __restrict__ out, W100 wts)
{
  const int lane = threadIdx.x & 63, wv = threadIdx.x >> 6;
  const int b = blockIdx.x * 4 + wv;
  const int n0 = lane * 4;
  float4 v  = make_float4(0.f, 0.f, 0.f, 0.f);
  float4 ii = make_float4(0.f, 0.f, 0.f, 0.f);
  const float4 w0 = *reinterpret_cast<const float4*>(&Wout[n0]);
  const float4 w1 = *reinterpret_cast<const float4*>(&Wout[H3 + n0]);
  const float bo0 = bout[0], bo1 = bout[1];
  float vo0 = 0.f, io0 = 0.f, vo1 = 0.f, io1 = 0.f;
  float acc0 = 0.0f, acc1 = 0.0f;
  for (int t = 0; t < TDIM; ++t) {
    const size_t o = ((size_t)t * BATCH + b) * H3 + n0;
    float4 cc = *reinterpret_cast<const float4*>(&c3[o]);
    float4 zz;
    lif_update(cc.x, v.x, ii.x, zz.x);
    lif_update(cc.y, v.y, ii.y, zz.y);
    lif_update(cc.z, v.z, ii.z, zz.z);
    lif_update(cc.w, v.w, ii.w, zz.w);
    float s0 = fmaf(zz.x, w0.x, fmaf(zz.y, w0.y, fmaf(zz.z, w0.z, zz.w * w0.w)));
    float s1 = fmaf(zz.x, w1.x, fmaf(zz.y, w1.y, fmaf(zz.z, w1.z, zz.w * w1.w)));
    #pragma unroll
    for (int m = 1; m < 64; m <<= 1) {
      s0 += __shfl_xor(s0, m);
      s1 += __shfl_xor(s1, m);
    }
    float zo0, zo1;
    lif_update(s0 + bo0, vo0, io0, zo0);
    lif_update(s1 + bo1, vo1, io1, zo1);
    acc0 += zo0 * wts.w[t];
    acc1 += zo1 * wts.w[t];
  }
  if (lane == 0) {
    const int oidx = b * ODIM;
    out[oidx]     = acc0;
    out[oidx + 1] = acc1;
  }
}

// ---------------- fp32 fallback path (round-1 kernels) ----------------
__global__ void fold1_kernel(const float* __restrict__ W1, const float* __restrict__ b1,
                             const float* __restrict__ g1, const float* __restrict__ bb1,
                             const float* __restrict__ m1, const float* __restrict__ v1,
                             const float* __restrict__ gi, const float* __restrict__ bi,
                             const float* __restrict__ mi, const float* __restrict__ vi,
                             float* __restrict__ W1f, float* __restrict__ e1) {
  const int j = blockIdx.x;
  const int tid = threadIdx.x;
  const float sg = g1[j] / sqrtf(v1[j] + 1e-5f);
  float part = 0.0f;
  for (int f = tid; f < FDIM; f += 256) {
    float si = gi[f] / sqrtf(vi[f] + 1e-5f);
    float h0 = bi[f] - mi[f] * si;
    float w  = W1[j * FDIM + f];
    part += w * h0;
    W1f[j * FDIM + f] = w * si * sg;
  }
  #pragma unroll
  for (int m = 1; m < 64; m <<= 1) part += __shfl_xor(part, m);
  __shared__ float red[4];
  if ((tid & 63) == 0) red[tid >> 6] = part;
  __syncthreads();
  if (tid == 0) {
    float d = red[0] + red[1] + red[2] + red[3];
    e1[j] = (d + b1[j] - m1[j]) * sg + bb1[j];
  }
}

__global__ void foldS_kernel(const float* __restrict__ W, const float* __restrict__ b,
                             const float* __restrict__ g, const float* __restrict__ bb,
                             const float* __restrict__ m, const float* __restrict__ v,
                             float* __restrict__ Wf, float* __restrict__ e, int K) {
  const int j = blockIdx.x;
  const float sg = g[j] / sqrtf(v[j] + 1e-5f);
  for (int k = threadIdx.x; k < K; k += 256)
    Wf[j * K + k] = W[j * K + k] * sg;
  if (threadIdx.x == 0) e[j] = (b[j] - m[j]) * sg + bb[j];
}

template<int TM, int TN, bool CONTIG>
__global__ __launch_bounds__(256, 2)
void gemm_lif_kernel(const float* __restrict__ A, size_t ars, size_t acs,
                     const float* __restrict__ W, const float* __restrict__ ebias,
                     float* __restrict__ vst, float* __restrict__ ist,
                     float* __restrict__ zout, int N, int K)
{
  constexpr int BK = 16;
  constexpr int BM = 16 * TM;
  constexpr int BN = 16 * TN;
  __shared__ float As[BK][BM];
  __shared__ float Bs[BK][BN];
  const int tid = threadIdx.x;
  const int tx = tid & 15, ty = tid >> 4;
  const int bn = blockIdx.x, bm = blockIdx.y;
  const float* Ablk = A + (size_t)bm * BM * ars;
  const float* Wblk = W + (size_t)bn * BN * (size_t)K;

  float acc[TM][TN];
  #pragma unroll
  for (int r = 0; r < TM; r++)
    #pragma unroll
    for (int c = 0; c < TN; c++) acc[r][c] = 0.0f;

  for (int k0 = 0; k0 < K; k0 += BK) {
    if (CONTIG) {
      constexpr int A4 = BM * BK / 4;
      #pragma unroll
      for (int q = 0; q < A4 / 256; q++) {
        int idx = q * 256 + tid;
        int r = idx >> 2;
        int kq = (idx & 3) << 2;
        float4 val = *reinterpret_cast<const float4*>(Ablk + (size_t)r * ars + (size_t)(k0 + kq));
        As[kq + 0][r] = val.x; As[kq + 1][r] = val.y;
        As[kq + 2][r] = val.z; As[kq + 3][r] = val.w;
      }
    } else {
      #pragma unroll
      for (int q = 0; q < BM * BK / 256; q++) {
        int idx = q * 256 + tid;
        int r = idx >> 4;
        int kk = idx & 15;
        As[kk][r] = Ablk[(size_t)r * ars + (size_t)(k0 + kk) * acs];
      }
    }
    {
      int n  = tid >> 2;
      int kq = (tid & 3) << 2;
      float4 val = *reinterpret_cast<const float4*>(Wblk + (size_t)n * K + (size_t)(k0 + kq));
      Bs[kq + 0][n] = val.x; Bs[kq + 1][n] = val.y;
      Bs[kq + 2][n] = val.z; Bs[kq + 3][n] = val.w;
    }
    __syncthreads();
    #pragma unroll
    for (int kk = 0; kk < BK; kk++) {
      float a[TM], bv[TN];
      const float4* ap = reinterpret_cast<const float4*>(&As[kk][ty * TM]);
      *reinterpret_cast<float4*>(&a[0]) = ap[0];
      if (TM == 8) *reinterpret_cast<float4*>(&a[4]) = ap[1];
      *reinterpret_cast<float4*>(&bv[0]) = *reinterpret_cast<const float4*>(&Bs[kk][tx * TN]);
      #pragma unroll
      for (int r = 0; r < TM; r++)
        #pragma unroll
        for (int c = 0; c < TN; c++)
          acc[r][c] = fmaf(a[r], bv[c], acc[r][c]);
    }
    __syncthreads();
  }

  const int n0 = bn * BN + tx * TN;
  const float4 ev = *reinterpret_cast<const float4*>(ebias + n0);
  #pragma unroll
  for (int r = 0; r < TM; r++) {
    const int brow = bm * BM + ty * TM + r;
    const size_t idx = (size_t)brow * N + n0;
    float c0 = acc[r][0] + ev.x;
    float c1 = acc[r][1] + ev.y;
    float c2 = acc[r][2] + ev.z;
    float c3 = acc[r][3] + ev.w;
    float4 vv = *reinterpret_cast<const float4*>(vst + idx);
    float4 ii = *reinterpret_cast<const float4*>(ist + idx);
    float4 zz;
    lif_update(c0, vv.x, ii.x, zz.x);
    lif_update(c1, vv.y, ii.y, zz.y);
    lif_update(c2, vv.z, ii.z, zz.z);
    lif_update(c3, vv.w, ii.w, zz.w);
    *reinterpret_cast<float4*>(zout + idx) = zz;
    *reinterpret_cast<float4*>(vst  + idx) = vv;
    *reinterpret_cast<float4*>(ist  + idx) = ii;
  }
}

__global__ void out_kernel(const float* __restrict__ z3, const float* __restrict__ Wout,
                           const float* __restrict__ bout, float* __restrict__ vo,
                           float* __restrict__ io, float* __restrict__ acc, float wt) {
  const int idx = blockIdx.x * 256 + threadIdx.x;
  if (idx >= BATCH * ODIM) return;
  const int b = idx >> 1, o = idx & 1;
  const float4* zr = reinterpret_cast<const float4*>(z3 + (size_t)b * H3);
  const float4* wr = reinterpret_cast<const float4*>(Wout + o * H3);
  float s = 0.0f;
  #pragma unroll 4
  for (int k = 0; k < H3 / 4; k++) {
    float4 zv = zr[k], wv = wr[k];
    s += zv.x * wv.x + zv.y * wv.y + zv.z * wv.z + zv.w * wv.w;
  }
  float cin = s + bout[o];
  float v = vo[idx], i = io[idx], z;
  lif_update(cin, v, i, z);
  vo[idx] = v; io[idx] = i;
  acc[idx] += z * wt;
}

extern "C" void kernel_launch(void* const* d_in, const int* in_sizes, int n_in,
                              void* d_out, int out_size, void* d_ws, size_t ws_size,
                              hipStream_t stream) {
  const float* x     = (const float*)d_in[0];
  const float* bni_g = (const float*)d_in[1];
  const float* bni_b = (const float*)d_in[2];
  const float* bni_m = (const float*)d_in[3];
  const float* bni_v = (const float*)d_in[4];
  const float* W1    = (const float*)d_in[5];
  const float* b1    = (const float*)d_in[6];
  const float* bn1_g = (const float*)d_in[7];
  const float* bn1_b = (const float*)d_in[8];
  const float* bn1_m = (const float*)d_in[9];
  const float* bn1_v = (const float*)d_in[10];
  const float* W2    = (const float*)d_in[11];
  const float* b2    = (const float*)d_in[12];
  const float* bn2_g = (const float*)d_in[13];
  const float* bn2_b = (const float*)d_in[14];
  const float* bn2_m = (const float*)d_in[15];
  const float* bn2_v = (const float*)d_in[16];
  const float* W3    = (const float*)d_in[17];
  const float* b3    = (const float*)d_in[18];
  const float* bn3_g = (const float*)d_in[19];
  const float* bn3_b = (const float*)d_in[20];
  const float* bn3_m = (const float*)d_in[21];
  const float* bn3_v = (const float*)d_in[22];
  const float* Wout  = (const float*)d_in[23];
  const float* bout  = (const float*)d_in[24];
  float* out = (float*)d_out;

  float* ws = (float*)d_ws;
  size_t off = 0;
  auto alloc = [&](size_t n) { float* p = ws + off; off += n; return p; };

  // ---- single-chunk big-GEMM path with region aliasing ----
  float* e1 = alloc(H1);
  float* e2 = alloc(H2);
  float* e3 = alloc(H3);
  float* s1 = alloc(H1);
  float* q2 = alloc(H2);
  float* q3 = alloc(H3);
  unsigned char* base = (unsigned char*)(ws + off);
  size_t boff = 0;
  auto carve = [&](size_t bytes) {
    void* p = base + boff;
    boff += (bytes + 255) & ~(size_t)255;
    return p;
  };
  _Float16* W1p   = (_Float16*)carve((size_t)2 * H1 * FDIM * 2);
  signed char* W2q = (signed char*)carve((size_t)4 * H2 * H1);
  signed char* W3q = (signed char*)carve((size_t)4 * H3 * H2);
  signed char* z1  = (signed char*)carve((size_t)M_ALL * H1);
  signed char* z2  = (signed char*)carve((size_t)M_ALL * H2);
  void* regionA = carve((size_t)2 * M_ALL * FDIM * 2);   // Xp (fp16 2-plane) / c2 (fp32)
  void* regionB = carve((size_t)M_ALL * H1 * 4);         // c1 (fp32) / c3 (fp32)
  _Float16* Xp = (_Float16*)regionA;
  float* c2    = (float*)regionA;
  float* c1    = (float*)regionB;
  float* c3    = (float*)regionB;
  const size_t needed = off * sizeof(float) + boff;

  if (ws_size >= needed) {
    // folds (independent)
    fold1_f16<<<H1, 256, 0, stream>>>(W1, b1, bn1_g, bn1_b, bn1_m, bn1_v,
                                      bni_g, bni_b, bni_m, bni_v, W1p, s1, e1);
    foldS_i8<<<H2, 256, 0, stream>>>(W2, b2, bn2_g, bn2_b, bn2_m, bn2_v, W2q, q2, e2, H2, H1);
    foldS_i8<<<H3, 256, 0, stream>>>(W3, b3, bn3_g, bn3_b, bn3_m, bn3_v, W3q, q3, e3, H3, H2);

    // serial layer chain over the full T at once
    tchunk_kernel<<<dim3(FDIM / 64, BATCH), 512, 0, stream>>>(x, Xp);
    g1c_kernel<<<(H1 / 128) * (M_ALL / 128), 256, 0, stream>>>(Xp, W1p, s1, e1, c1);
    scan_lif_kernel<<<BATCH * H1 / 1024, 256, 0, stream>>>(c1, z1, H1);
    gSc_kernel<128, 64, 2><<<(H2 / 64) * (M_ALL / 128), 256, 0, stream>>>(z1, W2q, q2, e2, c2, H2, H1);
    scan_lif_kernel<<<BATCH * H2 / 1024, 256, 0, stream>>>(c2, z2, H2);
    gSc_kernel<128, 32, 3><<<(H3 / 32) * (M_ALL / 128), 256, 0, stream>>>(z2, W3q, q3, e3, c3, H3, H2);
    W100 wts;
    for (int t = 0; t < TDIM; ++t)
      wts.w[t] = (float)std::pow(0.995, (double)(TDIM - 1 - t));
    scan3out_kernel<<<BATCH / 4, 256, 0, stream>>>(c3, Wout, bout, out, wts);
    return;
  }

  // ---- fp32 fallback (strided GEMM1, no transpose) ----
  off = 0;
  float* W1f = alloc((size_t)H1 * FDIM);
  float* W2f = alloc((size_t)H2 * H1);
  float* W3f = alloc((size_t)H3 * H2);
  float* fe1 = alloc(H1);
  float* fe2 = alloc(H2);
  float* fe3 = alloc(H3);
  float* fv1 = alloc((size_t)BATCH * H1);
  float* fi1 = alloc((size_t)BATCH * H1);
  float* fv2 = alloc((size_t)BATCH * H2);
  float* fi2 = alloc((size_t)BATCH * H2);
  float* fv3 = alloc((size_t)BATCH * H3);
  float* fi3 = alloc((size_t)BATCH * H3);
  float* fvo = alloc((size_t)BATCH * ODIM);
  float* fio = alloc((size_t)BATCH * ODIM);
  float* fz1 = alloc((size_t)BATCH * H1);
  float* fz2 = alloc((size_t)BATCH * H2);
  float* fz3 = alloc((size_t)BATCH * H3);

  const int nstate = BATCH * (2 * H1 + 2 * H2 + 2 * H3 + 2 * ODIM);
  zero_kernel<<<2048, 256, 0, stream>>>(fv1, nstate);
  zero_kernel<<<16, 256, 0, stream>>>(out, BATCH * ODIM);

  fold1_kernel<<<H1, 256, 0, stream>>>(W1, b1, bn1_g, bn1_b, bn1_m, bn1_v,
                                       bni_g, bni_b, bni_m, bni_v, W1f, fe1);
  foldS_kernel<<<H2, 256, 0, stream>>>(W2, b2, bn2_g, bn2_b, bn2_m, bn2_v, W2f, fe2, H1);
  foldS_kernel<<<H3, 256, 0, stream>>>(W3, b3, bn3_g, bn3_b, bn3_m, bn3_v, W3f, fe3, H2);

  const dim3 fg1(H1 / 64, BATCH / 128);
  const dim3 fg2(H2 / 64, BATCH / 64);
  const dim3 fg3(H3 / 64, BATCH / 64);

  for (int t = 0; t < TDIM; t++) {
    gemm_lif_kernel<8, 4, false><<<fg1, 256, 0, stream>>>(
        x + t, (size_t)FDIM * TDIM, TDIM, W1f, fe1, fv1, fi1, fz1, H1, FDIM);
    gemm_lif_kernel<4, 4, true><<<fg2, 256, 0, stream>>>(fz1, H1, 1, W2f, fe2, fv2, fi2, fz2, H2, H1);
    gemm_lif_kernel<4, 4, true><<<fg3, 256, 0, stream>>>(fz2, H2, 1, W3f, fe3, fv3, fi3, fz3, H3, H2);
    float wt = (float)std::pow(0.995, (double)(TDIM - 1 - t));
    out_kernel<<<BATCH * ODIM / 256, 256, 0, stream>>>(fz3, Wout, bout, fvo, fio, out, wt);
  }
}